// Round 1
// baseline (930.454 us; speedup 1.0000x reference)
//
#include <hip/hip_runtime.h>
#include <math.h>

namespace {
constexpr int B_ = 2, S_ = 2048, HID_ = 1024, NH_ = 16, HD_ = 64;
constexpr int M_ = B_ * S_;                 // 4096 rows
constexpr int QSZ = B_ * NH_ * S_ * HD_;    // 4194304 elements per tensor
constexpr int TBL = S_ * (HD_ / 2);         // 65536 cos/sin entries

// ---------------- RoPE cos/sin table ----------------
__global__ void rope_table_kernel(float* __restrict__ ct, float* __restrict__ st) {
  int t = blockIdx.x * blockDim.x + threadIdx.x;
  if (t >= TBL) return;
  int s = t >> 5, i = t & 31;
  // match reference: inv_freq in fp32, angle = s * inv_freq in fp32,
  // then high-precision trig on that angle.
  float inv = 1.0f / powf(10000.0f, (float)(2 * i) / (float)HD_);
  float ang = (float)s * inv;
  double a = (double)ang;
  ct[t] = (float)cos(a);
  st[t] = (float)sin(a);
}

// ---------------- QKV projection GEMM: out = hs @ W + b, stored [B,NH,S,HD] ----------------
__global__ __launch_bounds__(256)
void qkv_gemm_kernel(const float* __restrict__ hs, const float* __restrict__ W,
                     const float* __restrict__ bias, float* __restrict__ outp) {
  __shared__ float As[64][20];  // [m][k], pad 16->20 keeps float4 alignment, spreads banks
  __shared__ float Bs[16][64];  // [k][n]
  int tid = threadIdx.x;
  int ty = tid >> 4, tx = tid & 15;
  int m0 = blockIdx.x * 64;
  int n0 = blockIdx.y * 64;
  int arow = tid >> 2, ak = (tid & 3) * 4;   // 64 rows x 16 k
  int brow = tid >> 4, bcol = (tid & 15) * 4; // 16 k x 64 n
  float acc[4][4] = {};
  for (int k0 = 0; k0 < HID_; k0 += 16) {
    float4 av = *(const float4*)&hs[(size_t)(m0 + arow) * HID_ + k0 + ak];
    float4 bv = *(const float4*)&W[(size_t)(k0 + brow) * HID_ + n0 + bcol];
    __syncthreads();
    *(float4*)&As[arow][ak] = av;
    *(float4*)&Bs[brow][bcol] = bv;
    __syncthreads();
#pragma unroll
    for (int k = 0; k < 16; ++k) {
      float a0 = As[ty * 4 + 0][k];
      float a1 = As[ty * 4 + 1][k];
      float a2 = As[ty * 4 + 2][k];
      float a3 = As[ty * 4 + 3][k];
      float4 b4 = *(const float4*)&Bs[k][tx * 4];
      acc[0][0] += a0 * b4.x; acc[0][1] += a0 * b4.y; acc[0][2] += a0 * b4.z; acc[0][3] += a0 * b4.w;
      acc[1][0] += a1 * b4.x; acc[1][1] += a1 * b4.y; acc[1][2] += a1 * b4.z; acc[1][3] += a1 * b4.w;
      acc[2][0] += a2 * b4.x; acc[2][1] += a2 * b4.y; acc[2][2] += a2 * b4.z; acc[2][3] += a2 * b4.w;
      acc[3][0] += a3 * b4.x; acc[3][1] += a3 * b4.y; acc[3][2] += a3 * b4.z; acc[3][3] += a3 * b4.w;
    }
  }
  // epilogue: bias add, scatter to [B, NH, S, HD]; n-tile == HD so head = blockIdx.y
  int h = blockIdx.y;
  float4 bi = *(const float4*)&bias[n0 + tx * 4];
#pragma unroll
  for (int i = 0; i < 4; ++i) {
    int m = m0 + ty * 4 + i;
    int b = m / S_, s = m % S_;
    float4 r;
    r.x = acc[i][0] + bi.x;
    r.y = acc[i][1] + bi.y;
    r.z = acc[i][2] + bi.z;
    r.w = acc[i][3] + bi.w;
    *(float4*)&outp[(((size_t)b * NH_ + h) * S_ + s) * HD_ + tx * 4] = r;
  }
}

// ---------------- RoPE (in-place on q and k in ws) + q-scale ----------------
__global__ void rope_kernel(float* __restrict__ qp, float* __restrict__ kp,
                            const float* __restrict__ ct, const float* __restrict__ st) {
  constexpr int TOT = B_ * NH_ * S_ * (HD_ / 2);  // 2097152
  int t = blockIdx.x * blockDim.x + threadIdx.x;
  if (t >= 2 * TOT) return;
  float* p;
  float scale;
  int e;
  if (t < TOT) { p = qp; scale = 0.125f; e = t; }      // 64^-0.5
  else         { p = kp; scale = 1.0f;   e = t - TOT; }
  int i = e & 31;
  int s = (e >> 5) & (S_ - 1);
  int bh = e >> 16;
  size_t base = ((size_t)bh * S_ + s) * HD_;
  float x1 = p[base + i];
  float x2 = p[base + i + 32];
  float c = ct[s * 32 + i];
  float sn = st[s * 32 + i];
  p[base + i]      = scale * (x1 * c - x2 * sn);
  p[base + i + 32] = scale * (x2 * c + x1 * sn);
}

// ---------------- Flash attention (fp32, online softmax) ----------------
__global__ __launch_bounds__(256)
void attn_kernel(const float* __restrict__ qg, const float* __restrict__ kg,
                 const float* __restrict__ vg, const float* __restrict__ mask,
                 float* __restrict__ outp) {
  __shared__ float Qs[64][68];  // [qrow][d]
  __shared__ float Ks[64][68];  // [d][kcol]  (transposed)
  __shared__ float Vs[64][68];  // [krow][d]
  __shared__ float Ps[64][68];  // [qrow][kcol]
  int tid = threadIdx.x;
  int ty = tid >> 4, tx = tid & 15;
  int bh = blockIdx.y;
  int b = bh >> 4;  // NH = 16
  int q0 = blockIdx.x * 64;
  const float* qb = qg + (size_t)bh * S_ * HD_;
  const float* kb = kg + (size_t)bh * S_ * HD_;
  const float* vb = vg + (size_t)bh * S_ * HD_;
  int lrow = tid >> 2, ld0 = (tid & 3) * 16;

#pragma unroll
  for (int j = 0; j < 16; j += 4) {
    *(float4*)&Qs[lrow][ld0 + j] = *(const float4*)&qb[(size_t)(q0 + lrow) * HD_ + ld0 + j];
  }
  float mrun[4], lrun[4], O[4][4] = {};
#pragma unroll
  for (int i = 0; i < 4; ++i) { mrun[i] = -INFINITY; lrun[i] = 0.f; }

  for (int k0 = 0; k0 < S_; k0 += 64) {
    __syncthreads();  // previous iter done reading Ks/Vs/Ps
#pragma unroll
    for (int j = 0; j < 16; j += 4) {
      float4 kv = *(const float4*)&kb[(size_t)(k0 + lrow) * HD_ + ld0 + j];
      Ks[ld0 + j + 0][lrow] = kv.x;
      Ks[ld0 + j + 1][lrow] = kv.y;
      Ks[ld0 + j + 2][lrow] = kv.z;
      Ks[ld0 + j + 3][lrow] = kv.w;
      *(float4*)&Vs[lrow][ld0 + j] = *(const float4*)&vb[(size_t)(k0 + lrow) * HD_ + ld0 + j];
    }
    __syncthreads();

    // S = Q * K^T  (64x64, K-dim = 64)
    float sc[4][4] = {};
#pragma unroll 16
    for (int d = 0; d < 64; ++d) {
      float a0 = Qs[ty * 4 + 0][d];
      float a1 = Qs[ty * 4 + 1][d];
      float a2 = Qs[ty * 4 + 2][d];
      float a3 = Qs[ty * 4 + 3][d];
      float4 b4 = *(const float4*)&Ks[d][tx * 4];
      sc[0][0] += a0 * b4.x; sc[0][1] += a0 * b4.y; sc[0][2] += a0 * b4.z; sc[0][3] += a0 * b4.w;
      sc[1][0] += a1 * b4.x; sc[1][1] += a1 * b4.y; sc[1][2] += a1 * b4.z; sc[1][3] += a1 * b4.w;
      sc[2][0] += a2 * b4.x; sc[2][1] += a2 * b4.y; sc[2][2] += a2 * b4.z; sc[2][3] += a2 * b4.w;
      sc[3][0] += a3 * b4.x; sc[3][1] += a3 * b4.y; sc[3][2] += a3 * b4.z; sc[3][3] += a3 * b4.w;
    }
    // additive mask (broadcast over heads and q rows)
    float4 mk4 = *(const float4*)&mask[(size_t)b * S_ + k0 + tx * 4];
    float mk[4] = {mk4.x, mk4.y, mk4.z, mk4.w};

    // online softmax per row
#pragma unroll
    for (int i = 0; i < 4; ++i) {
      float rm = -INFINITY;
#pragma unroll
      for (int j = 0; j < 4; ++j) { sc[i][j] += mk[j]; rm = fmaxf(rm, sc[i][j]); }
      rm = fmaxf(rm, __shfl_xor(rm, 1));
      rm = fmaxf(rm, __shfl_xor(rm, 2));
      rm = fmaxf(rm, __shfl_xor(rm, 4));
      rm = fmaxf(rm, __shfl_xor(rm, 8));
      float mn = fmaxf(mrun[i], rm);
      float corr = expf(mrun[i] - mn);
      mrun[i] = mn;
      float p0 = expf(sc[i][0] - mn);
      float p1 = expf(sc[i][1] - mn);
      float p2 = expf(sc[i][2] - mn);
      float p3 = expf(sc[i][3] - mn);
      float rs = p0 + p1 + p2 + p3;
      rs += __shfl_xor(rs, 1);
      rs += __shfl_xor(rs, 2);
      rs += __shfl_xor(rs, 4);
      rs += __shfl_xor(rs, 8);
      lrun[i] = lrun[i] * corr + rs;
#pragma unroll
      for (int j = 0; j < 4; ++j) O[i][j] *= corr;
      float4 pw = {p0, p1, p2, p3};
      *(float4*)&Ps[ty * 4 + i][tx * 4] = pw;
    }
    __syncthreads();

    // O += P * V  (64x64 * 64x64)
#pragma unroll 16
    for (int kk = 0; kk < 64; ++kk) {
      float a0 = Ps[ty * 4 + 0][kk];
      float a1 = Ps[ty * 4 + 1][kk];
      float a2 = Ps[ty * 4 + 2][kk];
      float a3 = Ps[ty * 4 + 3][kk];
      float4 b4 = *(const float4*)&Vs[kk][tx * 4];
      O[0][0] += a0 * b4.x; O[0][1] += a0 * b4.y; O[0][2] += a0 * b4.z; O[0][3] += a0 * b4.w;
      O[1][0] += a1 * b4.x; O[1][1] += a1 * b4.y; O[1][2] += a1 * b4.z; O[1][3] += a1 * b4.w;
      O[2][0] += a2 * b4.x; O[2][1] += a2 * b4.y; O[2][2] += a2 * b4.z; O[2][3] += a2 * b4.w;
      O[3][0] += a3 * b4.x; O[3][1] += a3 * b4.y; O[3][2] += a3 * b4.z; O[3][3] += a3 * b4.w;
    }
  }

  // epilogue: normalize and write ctx [B, S, HID]
  int h = bh & 15;
#pragma unroll
  for (int i = 0; i < 4; ++i) {
    float inv = 1.0f / lrun[i];
    int s = q0 + ty * 4 + i;
    float4 r;
    r.x = O[i][0] * inv;
    r.y = O[i][1] * inv;
    r.z = O[i][2] * inv;
    r.w = O[i][3] * inv;
    *(float4*)&outp[((size_t)b * S_ + s) * HID_ + h * HD_ + tx * 4] = r;
  }
}

}  // namespace

extern "C" void kernel_launch(void* const* d_in, const int* in_sizes, int n_in,
                              void* d_out, int out_size, void* d_ws, size_t ws_size,
                              hipStream_t stream) {
  const float* hs   = (const float*)d_in[0];
  const float* mask = (const float*)d_in[1];
  const float* Wq   = (const float*)d_in[2];
  const float* bq   = (const float*)d_in[3];
  const float* Wk   = (const float*)d_in[4];
  const float* bk   = (const float*)d_in[5];
  const float* Wv   = (const float*)d_in[6];
  const float* bv   = (const float*)d_in[7];

  float* ws = (float*)d_ws;
  float* qw = ws;                 // [B,NH,S,HD]
  float* kw = ws + QSZ;
  float* vw = ws + 2 * (size_t)QSZ;
  float* ct = ws + 3 * (size_t)QSZ;
  float* st = ct + TBL;

  rope_table_kernel<<<(TBL + 255) / 256, 256, 0, stream>>>(ct, st);

  dim3 gg(M_ / 64, HID_ / 64);
  qkv_gemm_kernel<<<gg, 256, 0, stream>>>(hs, Wq, bq, qw);
  qkv_gemm_kernel<<<gg, 256, 0, stream>>>(hs, Wk, bk, kw);
  qkv_gemm_kernel<<<gg, 256, 0, stream>>>(hs, Wv, bv, vw);

  int tot = 2 * B_ * NH_ * S_ * (HD_ / 2);
  rope_kernel<<<(tot + 255) / 256, 256, 0, stream>>>(qw, kw, ct, st);

  attn_kernel<<<dim3(S_ / 64, B_ * NH_), 256, 0, stream>>>(qw, kw, vw, mask, (float*)d_out);
}

// Round 2
// 525.079 us; speedup vs baseline: 1.7720x; 1.7720x over previous
//
#include <hip/hip_runtime.h>
#include <math.h>

namespace {
constexpr int B_ = 2, S_ = 2048, HID_ = 1024, NH_ = 16, HD_ = 64;
constexpr int M_ = B_ * S_;                 // 4096 rows
constexpr int QSZ = B_ * NH_ * S_ * HD_;    // 4194304 elements per tensor
constexpr int TBL = S_ * (HD_ / 2);         // 65536 cos/sin entries

typedef float f32x4 __attribute__((ext_vector_type(4)));
typedef __bf16 bf16x8 __attribute__((ext_vector_type(8)));

__device__ inline unsigned short f2bf(float x) {
  unsigned int u = __float_as_uint(x);
  return (unsigned short)((u + 0x7fffu + ((u >> 16) & 1u)) >> 16);
}
__device__ inline float bf2f(unsigned short h) {
  return __uint_as_float(((unsigned int)h) << 16);
}

// ---------------- RoPE cos/sin table ----------------
__global__ void rope_table_kernel(float* __restrict__ ct, float* __restrict__ st) {
  int t = blockIdx.x * blockDim.x + threadIdx.x;
  if (t >= TBL) return;
  int s = t >> 5, i = t & 31;
  float inv = 1.0f / powf(10000.0f, (float)(2 * i) / (float)HD_);
  float ang = (float)s * inv;
  double a = (double)ang;
  ct[t] = (float)cos(a);
  st[t] = (float)sin(a);
}

// ---------------- QKV projection GEMM (fp32 core) with fused epilogues --------
// MODE 0: Q  -> rope + 1/8 scale + hi/lo bf16 split, layout [B,NH,S,HD]
// MODE 1: K  -> rope + hi/lo bf16 split,              layout [B,NH,S,HD]
// MODE 2: V  -> bf16, TRANSPOSED layout [B,NH,HD,S]
template <int MODE>
__global__ __launch_bounds__(256)
void qkv_gemm_kernel(const float* __restrict__ hs, const float* __restrict__ W,
                     const float* __restrict__ bias, unsigned short* __restrict__ out_hi,
                     unsigned short* __restrict__ out_lo,
                     const float* __restrict__ ct, const float* __restrict__ st) {
  __shared__ float As[64][20];
  __shared__ float Bs[16][64];
  int tid = threadIdx.x;
  int ty = tid >> 4, tx = tid & 15;
  int m0 = blockIdx.x * 64;
  int n0 = blockIdx.y * 64;
  int arow = tid >> 2, ak = (tid & 3) * 4;
  int brow = tid >> 4, bcol = (tid & 15) * 4;
  float acc[4][4] = {};
  for (int k0 = 0; k0 < HID_; k0 += 16) {
    float4 av = *(const float4*)&hs[(size_t)(m0 + arow) * HID_ + k0 + ak];
    float4 bv = *(const float4*)&W[(size_t)(k0 + brow) * HID_ + n0 + bcol];
    __syncthreads();
    *(float4*)&As[arow][ak] = av;
    *(float4*)&Bs[brow][bcol] = bv;
    __syncthreads();
#pragma unroll
    for (int k = 0; k < 16; ++k) {
      float a0 = As[ty * 4 + 0][k];
      float a1 = As[ty * 4 + 1][k];
      float a2 = As[ty * 4 + 2][k];
      float a3 = As[ty * 4 + 3][k];
      float4 b4 = *(const float4*)&Bs[k][tx * 4];
      acc[0][0] += a0 * b4.x; acc[0][1] += a0 * b4.y; acc[0][2] += a0 * b4.z; acc[0][3] += a0 * b4.w;
      acc[1][0] += a1 * b4.x; acc[1][1] += a1 * b4.y; acc[1][2] += a1 * b4.z; acc[1][3] += a1 * b4.w;
      acc[2][0] += a2 * b4.x; acc[2][1] += a2 * b4.y; acc[2][2] += a2 * b4.z; acc[2][3] += a2 * b4.w;
      acc[3][0] += a3 * b4.x; acc[3][1] += a3 * b4.y; acc[3][2] += a3 * b4.z; acc[3][3] += a3 * b4.w;
    }
  }
  int h = blockIdx.y;  // n-tile == HD, so blockIdx.y is the head
  float4 bi = *(const float4*)&bias[n0 + tx * 4];
  float bia[4] = {bi.x, bi.y, bi.z, bi.w};
#pragma unroll
  for (int i = 0; i < 4; ++i) {
    int m = m0 + ty * 4 + i;
    int b = m >> 11, s = m & (S_ - 1);
    float v[4];
#pragma unroll
    for (int j = 0; j < 4; ++j) v[j] = acc[i][j] + bia[j];
    if (MODE <= 1) {
      float r[4];
#pragma unroll
      for (int j = 0; j < 4; ++j) {
        float px = __shfl_xor(v[j], 8);   // partner holds d +- 32
        int d = tx * 4 + j, dm = d & 31;
        float c = ct[s * 32 + dm], sn = st[s * 32 + dm];
        r[j] = (d < 32) ? (v[j] * c - px * sn) : (v[j] * c + px * sn);
        if (MODE == 0) r[j] *= 0.125f;  // HD^-0.5
      }
      size_t base = (((size_t)b * NH_ + h) * S_ + s) * HD_ + tx * 4;
      short4 h4, l4;
      unsigned short hb;
      hb = f2bf(r[0]); h4.x = (short)hb; l4.x = (short)f2bf(r[0] - bf2f(hb));
      hb = f2bf(r[1]); h4.y = (short)hb; l4.y = (short)f2bf(r[1] - bf2f(hb));
      hb = f2bf(r[2]); h4.z = (short)hb; l4.z = (short)f2bf(r[2] - bf2f(hb));
      hb = f2bf(r[3]); h4.w = (short)hb; l4.w = (short)f2bf(r[3] - bf2f(hb));
      *(short4*)&out_hi[base] = h4;
      *(short4*)&out_lo[base] = l4;
    } else {
      size_t vbase = ((size_t)b * NH_ + h) * S_ * HD_;
#pragma unroll
      for (int j = 0; j < 4; ++j)
        out_hi[vbase + (size_t)(tx * 4 + j) * S_ + s] = f2bf(v[j]);
    }
  }
}

// ---------------- Flash attention on MFMA (split-bf16 QK^T, bf16 PV) ----------
__global__ __launch_bounds__(256, 4)
void attn_mfma_kernel(const unsigned short* __restrict__ qhi, const unsigned short* __restrict__ qlo,
                      const unsigned short* __restrict__ khi, const unsigned short* __restrict__ klo,
                      const unsigned short* __restrict__ vt, const float* __restrict__ mask,
                      float* __restrict__ outp) {
  __shared__ __align__(16) char smem[32768];
  constexpr int KHI = 0, KLO = 8192, VT = 16384, PP = 24576;
  const int tid = threadIdx.x;
  const int wave = tid >> 6, lane = tid & 63;
  const int lr = lane & 15, lg = lane >> 4;
  const int bh = blockIdx.y, b = bh >> 4, h = bh & 15;
  const int q0 = blockIdx.x * 64;
  const size_t hb = (size_t)bh * S_ * HD_;

  // Q fragments in registers: A row = lane&15, k = (lane>>4)*8 + j
  bf16x8 aq[2][2];
  {
    size_t base = hb + (size_t)(q0 + wave * 16 + lr) * HD_ + lg * 8;
    aq[0][0] = *(const bf16x8*)&qhi[base];
    aq[1][0] = *(const bf16x8*)&qhi[base + 32];
    aq[0][1] = *(const bf16x8*)&qlo[base];
    aq[1][1] = *(const bf16x8*)&qlo[base + 32];
  }

  f32x4 O[4];
  float mrun[4], lrun[4];
#pragma unroll
  for (int r = 0; r < 4; ++r) {
    O[r] = (f32x4){0.f, 0.f, 0.f, 0.f};
    mrun[r] = -INFINITY;
    lrun[r] = 0.f;
  }

  // staging: 2 chunks of 16B per thread per tensor
  const int srow0 = tid >> 3;       // 0..31
  const int srow1 = srow0 + 32;     // 32..63
  const int sseg = tid & 7;
  int l_off0 = (srow0 * 128 + sseg * 16) ^ ((srow0 & 7) << 4);
  int l_off1 = (srow1 * 128 + sseg * 16) ^ ((srow1 & 7) << 4);

  for (int k0 = 0; k0 < S_; k0 += 64) {
    __syncthreads();
    {
      size_t g0 = hb + (size_t)(k0 + srow0) * HD_ + sseg * 8;
      size_t g1 = hb + (size_t)(k0 + srow1) * HD_ + sseg * 8;
      bf16x8 k0h = *(const bf16x8*)&khi[g0];
      bf16x8 k1h = *(const bf16x8*)&khi[g1];
      bf16x8 k0l = *(const bf16x8*)&klo[g0];
      bf16x8 k1l = *(const bf16x8*)&klo[g1];
      size_t v0 = hb + (size_t)srow0 * S_ + k0 + sseg * 8;  // vt is [bh][d][s]
      size_t v1 = hb + (size_t)srow1 * S_ + k0 + sseg * 8;
      bf16x8 vv0 = *(const bf16x8*)&vt[v0];
      bf16x8 vv1 = *(const bf16x8*)&vt[v1];
      *(bf16x8*)(smem + KHI + l_off0) = k0h;
      *(bf16x8*)(smem + KHI + l_off1) = k1h;
      *(bf16x8*)(smem + KLO + l_off0) = k0l;
      *(bf16x8*)(smem + KLO + l_off1) = k1l;
      *(bf16x8*)(smem + VT + l_off0) = vv0;
      *(bf16x8*)(smem + VT + l_off1) = vv1;
    }
    __syncthreads();

    // S = Q K^T  (16 q-rows x 64 kv-cols per wave), split-bf16: hh + hl + lh
    f32x4 sc[4];
#pragma unroll
    for (int c = 0; c < 4; ++c) sc[c] = (f32x4){0.f, 0.f, 0.f, 0.f};
#pragma unroll
    for (int t = 0; t < 2; ++t) {
#pragma unroll
      for (int c = 0; c < 4; ++c) {
        int n = c * 16 + lr;
        int off = (n * 128 + t * 64 + lg * 16) ^ ((n & 7) << 4);
        bf16x8 bhv = *(const bf16x8*)(smem + KHI + off);
        bf16x8 blv = *(const bf16x8*)(smem + KLO + off);
        sc[c] = __builtin_amdgcn_mfma_f32_16x16x32_bf16(aq[t][0], bhv, sc[c], 0, 0, 0);
        sc[c] = __builtin_amdgcn_mfma_f32_16x16x32_bf16(aq[t][0], blv, sc[c], 0, 0, 0);
        sc[c] = __builtin_amdgcn_mfma_f32_16x16x32_bf16(aq[t][1], bhv, sc[c], 0, 0, 0);
      }
    }

    float mk[4];
#pragma unroll
    for (int c = 0; c < 4; ++c) mk[c] = mask[(size_t)b * S_ + k0 + c * 16 + lr];

    // online softmax; rows r live at D row = lg*4 + r, col = c*16 + lr
#pragma unroll
    for (int r = 0; r < 4; ++r) {
      float s0 = sc[0][r] + mk[0], s1 = sc[1][r] + mk[1];
      float s2 = sc[2][r] + mk[2], s3 = sc[3][r] + mk[3];
      float mx = fmaxf(fmaxf(s0, s1), fmaxf(s2, s3));
      mx = fmaxf(mx, __shfl_xor(mx, 1));
      mx = fmaxf(mx, __shfl_xor(mx, 2));
      mx = fmaxf(mx, __shfl_xor(mx, 4));
      mx = fmaxf(mx, __shfl_xor(mx, 8));
      float mn = fmaxf(mrun[r], mx);
      float corr = __expf(mrun[r] - mn);
      mrun[r] = mn;
      int prow = wave * 16 + lg * 4 + r;
      int sw = (prow & 7) << 4;
      float rs = 0.f;
      unsigned short pb;
      pb = f2bf(__expf(s0 - mn)); rs += bf2f(pb);
      *(unsigned short*)(smem + PP + ((prow * 128 + (0 * 16 + lr) * 2) ^ sw)) = pb;
      pb = f2bf(__expf(s1 - mn)); rs += bf2f(pb);
      *(unsigned short*)(smem + PP + ((prow * 128 + (1 * 16 + lr) * 2) ^ sw)) = pb;
      pb = f2bf(__expf(s2 - mn)); rs += bf2f(pb);
      *(unsigned short*)(smem + PP + ((prow * 128 + (2 * 16 + lr) * 2) ^ sw)) = pb;
      pb = f2bf(__expf(s3 - mn)); rs += bf2f(pb);
      *(unsigned short*)(smem + PP + ((prow * 128 + (3 * 16 + lr) * 2) ^ sw)) = pb;
      rs += __shfl_xor(rs, 1);
      rs += __shfl_xor(rs, 2);
      rs += __shfl_xor(rs, 4);
      rs += __shfl_xor(rs, 8);
      lrun[r] = lrun[r] * corr + rs;
      O[0][r] *= corr; O[1][r] *= corr; O[2][r] *= corr; O[3][r] *= corr;
    }

    // O += P V : A = P (row = lane&15 within wave's 16 rows, k = kv), B = V^T tile
    bf16x8 ap[2];
    {
      int prow = wave * 16 + lr;
      int swp = (prow & 7) << 4;
      ap[0] = *(const bf16x8*)(smem + PP + ((prow * 128 + 0 + lg * 16) ^ swp));
      ap[1] = *(const bf16x8*)(smem + PP + ((prow * 128 + 64 + lg * 16) ^ swp));
    }
#pragma unroll
    for (int t = 0; t < 2; ++t) {
#pragma unroll
      for (int dt = 0; dt < 4; ++dt) {
        int n = dt * 16 + lr;
        int off = (n * 128 + t * 64 + lg * 16) ^ ((n & 7) << 4);
        bf16x8 bv = *(const bf16x8*)(smem + VT + off);
        O[dt] = __builtin_amdgcn_mfma_f32_16x16x32_bf16(ap[t], bv, O[dt], 0, 0, 0);
      }
    }
  }

  // epilogue: normalize, write ctx [B, S, HID] fp32
#pragma unroll
  for (int r = 0; r < 4; ++r) {
    float inv = 1.0f / lrun[r];
    int s = q0 + wave * 16 + lg * 4 + r;
    size_t rowb = ((size_t)b * S_ + s) * HID_ + h * HD_;
#pragma unroll
    for (int dt = 0; dt < 4; ++dt)
      outp[rowb + dt * 16 + lr] = O[dt][r] * inv;
  }
}

}  // namespace

extern "C" void kernel_launch(void* const* d_in, const int* in_sizes, int n_in,
                              void* d_out, int out_size, void* d_ws, size_t ws_size,
                              hipStream_t stream) {
  const float* hs   = (const float*)d_in[0];
  const float* mask = (const float*)d_in[1];
  const float* Wq   = (const float*)d_in[2];
  const float* bq   = (const float*)d_in[3];
  const float* Wk   = (const float*)d_in[4];
  const float* bk   = (const float*)d_in[5];
  const float* Wv   = (const float*)d_in[6];
  const float* bv   = (const float*)d_in[7];

  unsigned short* qhi = (unsigned short*)d_ws;
  unsigned short* qlo = qhi + QSZ;
  unsigned short* khi = qlo + QSZ;
  unsigned short* klo = khi + QSZ;
  unsigned short* vt  = klo + QSZ;   // [B,NH,HD,S] transposed
  float* ct = (float*)(vt + QSZ);
  float* st = ct + TBL;

  rope_table_kernel<<<TBL / 256, 256, 0, stream>>>(ct, st);

  dim3 gg(M_ / 64, HID_ / 64);
  qkv_gemm_kernel<0><<<gg, 256, 0, stream>>>(hs, Wq, bq, qhi, qlo, ct, st);
  qkv_gemm_kernel<1><<<gg, 256, 0, stream>>>(hs, Wk, bk, khi, klo, ct, st);
  qkv_gemm_kernel<2><<<gg, 256, 0, stream>>>(hs, Wv, bv, vt, nullptr, ct, st);

  attn_mfma_kernel<<<dim3(S_ / 64, B_ * NH_), 256, 0, stream>>>(qhi, qlo, khi, klo, vt, mask,
                                                                (float*)d_out);
}

// Round 3
// 209.741 us; speedup vs baseline: 4.4362x; 2.5035x over previous
//
#include <hip/hip_runtime.h>
#include <math.h>

namespace {
constexpr int B_ = 2, S_ = 2048, HID_ = 1024, NH_ = 16, HD_ = 64;
constexpr int M_ = B_ * S_;                 // 4096 rows
constexpr int QSZ = B_ * NH_ * S_ * HD_;    // 4194304 elements per tensor
constexpr int TBL = S_ * (HD_ / 2);         // 65536 cos/sin entries

typedef float f32x4 __attribute__((ext_vector_type(4)));
typedef __bf16 bf16x8 __attribute__((ext_vector_type(8)));
typedef unsigned short u16;

__device__ inline u16 f2bf(float x) {
  unsigned int u = __float_as_uint(x);
  return (u16)((u + 0x7fffu + ((u >> 16) & 1u)) >> 16);
}
__device__ inline float bf2f(u16 h) {
  return __uint_as_float(((unsigned int)h) << 16);
}

typedef __attribute__((address_space(1))) const unsigned int as1_u32;
typedef __attribute__((address_space(3))) unsigned int as3_u32;
__device__ __forceinline__ void gll16(const void* g, void* l) {
  __builtin_amdgcn_global_load_lds((as1_u32*)g, (as3_u32*)l, 16, 0, 0);
}

// ---------------- RoPE cos/sin table ----------------
__global__ void rope_table_kernel(float* __restrict__ ct, float* __restrict__ st) {
  int t = blockIdx.x * blockDim.x + threadIdx.x;
  if (t >= TBL) return;
  int s = t >> 5, i = t & 31;
  float inv = 1.0f / powf(10000.0f, (float)(2 * i) / (float)HD_);
  float ang = (float)s * inv;
  double a = (double)ang;
  ct[t] = (float)cos(a);
  st[t] = (float)sin(a);
}

// ---------------- hs -> bf16 hi/lo split ----------------
__global__ __launch_bounds__(256)
void convert_hs_kernel(const float* __restrict__ hs, u16* __restrict__ hhi, u16* __restrict__ hlo) {
  size_t t = (size_t)blockIdx.x * 256 + threadIdx.x;
  float4 v = *(const float4*)&hs[t * 4];
  u16 h0 = f2bf(v.x), h1 = f2bf(v.y), h2 = f2bf(v.z), h3 = f2bf(v.w);
  short4 hi = {(short)h0, (short)h1, (short)h2, (short)h3};
  short4 lo = {(short)f2bf(v.x - bf2f(h0)), (short)f2bf(v.y - bf2f(h1)),
               (short)f2bf(v.z - bf2f(h2)), (short)f2bf(v.w - bf2f(h3))};
  *(short4*)&hhi[t * 4] = hi;
  *(short4*)&hlo[t * 4] = lo;
}

// ---------------- W -> W^T bf16  (wt[3][n][k]) ----------------
__global__ __launch_bounds__(256)
void transpose_w_kernel(const float* __restrict__ Wq, const float* __restrict__ Wk,
                        const float* __restrict__ Wv, u16* __restrict__ wt) {
  __shared__ float tile[64][65];
  const float* W = blockIdx.z == 0 ? Wq : blockIdx.z == 1 ? Wk : Wv;
  int k0 = blockIdx.x * 64, n0 = blockIdx.y * 64;
  int t = threadIdx.x;
  int lrow = t >> 4, lcol = (t & 15) * 4;
#pragma unroll
  for (int i = 0; i < 4; ++i) {
    float4 v = *(const float4*)&W[(size_t)(k0 + lrow + i * 16) * HID_ + n0 + lcol];
    tile[lrow + i * 16][lcol + 0] = v.x;
    tile[lrow + i * 16][lcol + 1] = v.y;
    tile[lrow + i * 16][lcol + 2] = v.z;
    tile[lrow + i * 16][lcol + 3] = v.w;
  }
  __syncthreads();
  int n = t >> 2, ks = (t & 3) * 16;
  u16 tmp[16];
#pragma unroll
  for (int j = 0; j < 16; ++j) tmp[j] = f2bf(tile[ks + j][n]);
  u16* dst = &wt[((size_t)blockIdx.z * 1024 + n0 + n) * 1024 + k0 + ks];
  ((uint4*)dst)[0] = ((uint4*)tmp)[0];
  ((uint4*)dst)[1] = ((uint4*)tmp)[1];
}

// ---------------- Fused QKV projection on MFMA ----------------
// C[m][n] = hs[m][:] . W^T[n][:],  n in [0,3072) = Q|K|V.
// Split-A: C = A_hi*B + A_lo*B  (B = W^T bf16).
// Epilogue: Q/K -> bias+rope(+scale)+hi/lo bf16 [B,NH,S,HD]; V -> bias+bf16 [B,NH,HD,S].
__global__ __launch_bounds__(256)
void proj_gemm_kernel(const u16* __restrict__ Ah, const u16* __restrict__ Al,
                      const u16* __restrict__ Wt,
                      const float* __restrict__ bq, const float* __restrict__ bk,
                      const float* __restrict__ bv,
                      const float* __restrict__ ct, const float* __restrict__ st,
                      u16* __restrict__ qhi, u16* __restrict__ qlo,
                      u16* __restrict__ khi, u16* __restrict__ klo, u16* __restrict__ vt) {
  __shared__ u16 sAh[128 * 64];
  __shared__ u16 sAl[128 * 64];
  __shared__ u16 sB[128 * 64];
  const int tid = threadIdx.x;
  const int wave = tid >> 6, lane = tid & 63;
  const int lr = lane & 15, lg = lane >> 4;

  // XCD-chunked swizzle: 768 blocks, 96 per XCD, gx-major so each XCD shares 4 A-panels.
  int bid = blockIdx.x;
  int swz = (bid & 7) * 96 + (bid >> 3);
  const int gx = swz / 24, gy = swz % 24;
  const int m0 = gx * 128;
  const int ng0 = gy * 128;  // global n in [0,3072)

  // staging address precompute (source pre-swizzled kseg)
  size_t aoff[4], boff[4];
  int c16[4];
#pragma unroll
  for (int i = 0; i < 4; ++i) {
    int c = i * 256 + tid;
    int row = c >> 3, ks = c & 7;
    int kph = (ks ^ (row & 7)) * 8;
    aoff[i] = (size_t)(m0 + row) * HID_ + kph;
    boff[i] = (size_t)(ng0 + row) * HID_ + kph;
    c16[i] = c * 16;
  }

  // fragment read offsets (swizzled)
  const int wr = (wave >> 1) * 64, wc = (wave & 1) * 64;
  int offA[4][2], offB[4][2];
#pragma unroll
  for (int f = 0; f < 4; ++f) {
    int ra = wr + f * 16 + lr;
    int rb = wc + f * 16 + lr;
#pragma unroll
    for (int kk = 0; kk < 2; ++kk) {
      offA[f][kk] = ra * 128 + (((kk * 4 + lg)) ^ (ra & 7)) * 16;
      offB[f][kk] = rb * 128 + (((kk * 4 + lg)) ^ (rb & 7)) * 16;
    }
  }

  f32x4 acc[4][4];
#pragma unroll
  for (int mf = 0; mf < 4; ++mf)
#pragma unroll
    for (int nf = 0; nf < 4; ++nf) acc[mf][nf] = (f32x4){0.f, 0.f, 0.f, 0.f};

  for (int k0 = 0; k0 < HID_; k0 += 64) {
    __syncthreads();
#pragma unroll
    for (int i = 0; i < 4; ++i) {
      gll16(Ah + aoff[i] + k0, (char*)sAh + c16[i]);
      gll16(Al + aoff[i] + k0, (char*)sAl + c16[i]);
      gll16(Wt + boff[i] + k0, (char*)sB + c16[i]);
    }
    __syncthreads();
#pragma unroll
    for (int kk = 0; kk < 2; ++kk) {
      bf16x8 a_h[4], a_l[4], bb[4];
#pragma unroll
      for (int f = 0; f < 4; ++f) {
        a_h[f] = *(const bf16x8*)((const char*)sAh + offA[f][kk]);
        a_l[f] = *(const bf16x8*)((const char*)sAl + offA[f][kk]);
        bb[f] = *(const bf16x8*)((const char*)sB + offB[f][kk]);
      }
#pragma unroll
      for (int mf = 0; mf < 4; ++mf)
#pragma unroll
        for (int nf = 0; nf < 4; ++nf) {
          acc[mf][nf] = __builtin_amdgcn_mfma_f32_16x16x32_bf16(a_h[mf], bb[nf], acc[mf][nf], 0, 0, 0);
          acc[mf][nf] = __builtin_amdgcn_mfma_f32_16x16x32_bf16(a_l[mf], bb[nf], acc[mf][nf], 0, 0, 0);
        }
    }
  }

  // ---- epilogue ----
  const int which = gy >> 3;            // 0 Q, 1 K, 2 V
  const int colm = (gy & 7) * 128 + wc; // column base within the 1024-wide matrix
  const int h = colm >> 6;              // head
  const float* bias = which == 0 ? bq : which == 1 ? bk : bv;
  const float scale = which == 0 ? 0.125f : 1.0f;

  if (which < 2) {
    u16* oh = which == 0 ? qhi : khi;
    u16* ol = which == 0 ? qlo : klo;
#pragma unroll
    for (int mf = 0; mf < 4; ++mf) {
#pragma unroll
      for (int r = 0; r < 4; ++r) {
        int m = m0 + wr + mf * 16 + lg * 4 + r;
        int b = m >> 11, s = m & (S_ - 1);
        size_t rowb = (((size_t)b * NH_ + h) * S_ + s) * HD_;
#pragma unroll
        for (int nf = 0; nf < 2; ++nf) {
          int d = nf * 16 + lr;
          float x1 = acc[mf][nf][r] + bias[colm + d];
          float x2 = acc[mf][nf + 2][r] + bias[colm + d + 32];
          float cth = ct[s * 32 + d], sth = st[s * 32 + d];
          float r1 = (x1 * cth - x2 * sth) * scale;
          float r2 = (x2 * cth + x1 * sth) * scale;
          u16 hb1 = f2bf(r1);
          oh[rowb + d] = hb1;
          ol[rowb + d] = f2bf(r1 - bf2f(hb1));
          u16 hb2 = f2bf(r2);
          oh[rowb + d + 32] = hb2;
          ol[rowb + d + 32] = f2bf(r2 - bf2f(hb2));
        }
      }
    }
  } else {
#pragma unroll
    for (int mf = 0; mf < 4; ++mf) {
      int mB = m0 + wr + mf * 16 + lg * 4;
      int b = mB >> 11, s0 = mB & (S_ - 1);
#pragma unroll
      for (int nf = 0; nf < 4; ++nf) {
        int d = nf * 16 + lr;
        float bi = bias[colm + d];
        ushort4 pk;
        pk.x = f2bf(acc[mf][nf][0] + bi);
        pk.y = f2bf(acc[mf][nf][1] + bi);
        pk.z = f2bf(acc[mf][nf][2] + bi);
        pk.w = f2bf(acc[mf][nf][3] + bi);
        *(ushort4*)&vt[(((size_t)b * NH_ + h) * HD_ + d) * S_ + s0] = pk;
      }
    }
  }
}

// ---------------- Flash attention on MFMA (split-bf16 QK^T, bf16 PV) ----------
__global__ __launch_bounds__(256, 4)
void attn_mfma_kernel(const u16* __restrict__ qhi, const u16* __restrict__ qlo,
                      const u16* __restrict__ khi, const u16* __restrict__ klo,
                      const u16* __restrict__ vt, const float* __restrict__ mask,
                      float* __restrict__ outp) {
  __shared__ __align__(16) char smem[32768];
  constexpr int KHI = 0, KLO = 8192, VT = 16384, PP = 24576;
  const int tid = threadIdx.x;
  const int wave = tid >> 6, lane = tid & 63;
  const int lr = lane & 15, lg = lane >> 4;
  const int bh = blockIdx.y, b = bh >> 4, h = bh & 15;
  const int q0 = blockIdx.x * 64;
  const size_t hb = (size_t)bh * S_ * HD_;

  bf16x8 aq[2][2];
  {
    size_t base = hb + (size_t)(q0 + wave * 16 + lr) * HD_ + lg * 8;
    aq[0][0] = *(const bf16x8*)&qhi[base];
    aq[1][0] = *(const bf16x8*)&qhi[base + 32];
    aq[0][1] = *(const bf16x8*)&qlo[base];
    aq[1][1] = *(const bf16x8*)&qlo[base + 32];
  }

  f32x4 O[4];
  float mrun[4], lrun[4];
#pragma unroll
  for (int r = 0; r < 4; ++r) {
    O[r] = (f32x4){0.f, 0.f, 0.f, 0.f};
    mrun[r] = -INFINITY;
    lrun[r] = 0.f;
  }

  const int srow0 = tid >> 3;
  const int srow1 = srow0 + 32;
  const int sseg = tid & 7;
  int l_off0 = (srow0 * 128 + sseg * 16) ^ ((srow0 & 7) << 4);
  int l_off1 = (srow1 * 128 + sseg * 16) ^ ((srow1 & 7) << 4);

  for (int k0 = 0; k0 < S_; k0 += 64) {
    __syncthreads();
    {
      size_t g0 = hb + (size_t)(k0 + srow0) * HD_ + sseg * 8;
      size_t g1 = hb + (size_t)(k0 + srow1) * HD_ + sseg * 8;
      bf16x8 k0h = *(const bf16x8*)&khi[g0];
      bf16x8 k1h = *(const bf16x8*)&khi[g1];
      bf16x8 k0l = *(const bf16x8*)&klo[g0];
      bf16x8 k1l = *(const bf16x8*)&klo[g1];
      size_t v0 = hb + (size_t)srow0 * S_ + k0 + sseg * 8;
      size_t v1 = hb + (size_t)srow1 * S_ + k0 + sseg * 8;
      bf16x8 vv0 = *(const bf16x8*)&vt[v0];
      bf16x8 vv1 = *(const bf16x8*)&vt[v1];
      *(bf16x8*)(smem + KHI + l_off0) = k0h;
      *(bf16x8*)(smem + KHI + l_off1) = k1h;
      *(bf16x8*)(smem + KLO + l_off0) = k0l;
      *(bf16x8*)(smem + KLO + l_off1) = k1l;
      *(bf16x8*)(smem + VT + l_off0) = vv0;
      *(bf16x8*)(smem + VT + l_off1) = vv1;
    }
    __syncthreads();

    f32x4 sc[4];
#pragma unroll
    for (int c = 0; c < 4; ++c) sc[c] = (f32x4){0.f, 0.f, 0.f, 0.f};
#pragma unroll
    for (int t = 0; t < 2; ++t) {
#pragma unroll
      for (int c = 0; c < 4; ++c) {
        int n = c * 16 + lr;
        int off = (n * 128 + t * 64 + lg * 16) ^ ((n & 7) << 4);
        bf16x8 bhv = *(const bf16x8*)(smem + KHI + off);
        bf16x8 blv = *(const bf16x8*)(smem + KLO + off);
        sc[c] = __builtin_amdgcn_mfma_f32_16x16x32_bf16(aq[t][0], bhv, sc[c], 0, 0, 0);
        sc[c] = __builtin_amdgcn_mfma_f32_16x16x32_bf16(aq[t][0], blv, sc[c], 0, 0, 0);
        sc[c] = __builtin_amdgcn_mfma_f32_16x16x32_bf16(aq[t][1], bhv, sc[c], 0, 0, 0);
      }
    }

    float mk[4];
#pragma unroll
    for (int c = 0; c < 4; ++c) mk[c] = mask[(size_t)b * S_ + k0 + c * 16 + lr];

#pragma unroll
    for (int r = 0; r < 4; ++r) {
      float s0 = sc[0][r] + mk[0], s1 = sc[1][r] + mk[1];
      float s2 = sc[2][r] + mk[2], s3 = sc[3][r] + mk[3];
      float mx = fmaxf(fmaxf(s0, s1), fmaxf(s2, s3));
      mx = fmaxf(mx, __shfl_xor(mx, 1));
      mx = fmaxf(mx, __shfl_xor(mx, 2));
      mx = fmaxf(mx, __shfl_xor(mx, 4));
      mx = fmaxf(mx, __shfl_xor(mx, 8));
      float mn = fmaxf(mrun[r], mx);
      float corr = __expf(mrun[r] - mn);
      mrun[r] = mn;
      int prow = wave * 16 + lg * 4 + r;
      int sw = (prow & 7) << 4;
      float rs = 0.f;
      u16 pb;
      pb = f2bf(__expf(s0 - mn)); rs += bf2f(pb);
      *(u16*)(smem + PP + ((prow * 128 + (0 * 16 + lr) * 2) ^ sw)) = pb;
      pb = f2bf(__expf(s1 - mn)); rs += bf2f(pb);
      *(u16*)(smem + PP + ((prow * 128 + (1 * 16 + lr) * 2) ^ sw)) = pb;
      pb = f2bf(__expf(s2 - mn)); rs += bf2f(pb);
      *(u16*)(smem + PP + ((prow * 128 + (2 * 16 + lr) * 2) ^ sw)) = pb;
      pb = f2bf(__expf(s3 - mn)); rs += bf2f(pb);
      *(u16*)(smem + PP + ((prow * 128 + (3 * 16 + lr) * 2) ^ sw)) = pb;
      rs += __shfl_xor(rs, 1);
      rs += __shfl_xor(rs, 2);
      rs += __shfl_xor(rs, 4);
      rs += __shfl_xor(rs, 8);
      lrun[r] = lrun[r] * corr + rs;
      O[0][r] *= corr; O[1][r] *= corr; O[2][r] *= corr; O[3][r] *= corr;
    }

    bf16x8 ap[2];
    {
      int prow = wave * 16 + lr;
      int swp = (prow & 7) << 4;
      ap[0] = *(const bf16x8*)(smem + PP + ((prow * 128 + 0 + lg * 16) ^ swp));
      ap[1] = *(const bf16x8*)(smem + PP + ((prow * 128 + 64 + lg * 16) ^ swp));
    }
#pragma unroll
    for (int t = 0; t < 2; ++t) {
#pragma unroll
      for (int dt = 0; dt < 4; ++dt) {
        int n = dt * 16 + lr;
        int off = (n * 128 + t * 64 + lg * 16) ^ ((n & 7) << 4);
        bf16x8 bv = *(const bf16x8*)(smem + VT + off);
        O[dt] = __builtin_amdgcn_mfma_f32_16x16x32_bf16(ap[t], bv, O[dt], 0, 0, 0);
      }
    }
  }

#pragma unroll
  for (int r = 0; r < 4; ++r) {
    float inv = 1.0f / lrun[r];
    int s = q0 + wave * 16 + lg * 4 + r;
    size_t rowb = ((size_t)b * S_ + s) * HID_ + h * HD_;
#pragma unroll
    for (int dt = 0; dt < 4; ++dt)
      outp[rowb + dt * 16 + lr] = O[dt][r] * inv;
  }
}

}  // namespace

extern "C" void kernel_launch(void* const* d_in, const int* in_sizes, int n_in,
                              void* d_out, int out_size, void* d_ws, size_t ws_size,
                              hipStream_t stream) {
  const float* hs   = (const float*)d_in[0];
  const float* mask = (const float*)d_in[1];
  const float* Wq   = (const float*)d_in[2];
  const float* bq   = (const float*)d_in[3];
  const float* Wk   = (const float*)d_in[4];
  const float* bk   = (const float*)d_in[5];
  const float* Wv   = (const float*)d_in[6];
  const float* bv   = (const float*)d_in[7];

  u16* qhi = (u16*)d_ws;
  u16* qlo = qhi + QSZ;
  u16* khi = qlo + QSZ;
  u16* klo = khi + QSZ;
  u16* vt  = klo + QSZ;                 // [B,NH,HD,S]
  u16* hhi = vt + QSZ;                  // [M, HID]
  u16* hlo = hhi + (size_t)M_ * HID_;
  u16* wt  = hlo + (size_t)M_ * HID_;   // [3][1024][1024] transposed
  float* ct = (float*)(wt + (size_t)3 * 1024 * 1024);
  float* st = ct + TBL;

  rope_table_kernel<<<TBL / 256, 256, 0, stream>>>(ct, st);
  convert_hs_kernel<<<(M_ * HID_) / 1024, 256, 0, stream>>>(hs, hhi, hlo);
  transpose_w_kernel<<<dim3(16, 16, 3), 256, 0, stream>>>(Wq, Wk, Wv, wt);

  proj_gemm_kernel<<<768, 256, 0, stream>>>(hhi, hlo, wt, bq, bk, bv, ct, st,
                                            qhi, qlo, khi, klo, vt);

  attn_mfma_kernel<<<dim3(S_ / 64, B_ * NH_), 256, 0, stream>>>(qhi, qlo, khi, klo, vt, mask,
                                                                (float*)d_out);
}

// Round 4
// 188.330 us; speedup vs baseline: 4.9406x; 1.1137x over previous
//
#include <hip/hip_runtime.h>
#include <math.h>

namespace {
constexpr int B_ = 2, S_ = 2048, HID_ = 1024, NH_ = 16, HD_ = 64;
constexpr int M_ = B_ * S_;                 // 4096 rows
constexpr int QSZ = B_ * NH_ * S_ * HD_;    // 4194304 elements per tensor
constexpr int TBL = S_ * (HD_ / 2);         // 65536 cos/sin entries

typedef float f32x4 __attribute__((ext_vector_type(4)));
typedef __bf16 bf16x8 __attribute__((ext_vector_type(8)));
typedef unsigned short u16;

__device__ inline u16 f2bf(float x) {
  unsigned int u = __float_as_uint(x);
  return (u16)((u + 0x7fffu + ((u >> 16) & 1u)) >> 16);
}
__device__ inline float bf2f(u16 h) {
  return __uint_as_float(((unsigned int)h) << 16);
}

typedef __attribute__((address_space(1))) const unsigned int as1_u32;
typedef __attribute__((address_space(3))) unsigned int as3_u32;
__device__ __forceinline__ void gll16(const void* g, void* l) {
  __builtin_amdgcn_global_load_lds((as1_u32*)g, (as3_u32*)l, 16, 0, 0);
}

// ---------------- RoPE cos/sin table ----------------
__global__ void rope_table_kernel(float* __restrict__ ct, float* __restrict__ st) {
  int t = blockIdx.x * blockDim.x + threadIdx.x;
  if (t >= TBL) return;
  int s = t >> 5, i = t & 31;
  float inv = 1.0f / powf(10000.0f, (float)(2 * i) / (float)HD_);
  float ang = (float)s * inv;
  double a = (double)ang;
  ct[t] = (float)cos(a);
  st[t] = (float)sin(a);
}

// ---------------- hs -> bf16 hi/lo split ----------------
__global__ __launch_bounds__(256)
void convert_hs_kernel(const float* __restrict__ hs, u16* __restrict__ hhi, u16* __restrict__ hlo) {
  size_t t = (size_t)blockIdx.x * 256 + threadIdx.x;
  float4 v = *(const float4*)&hs[t * 4];
  u16 h0 = f2bf(v.x), h1 = f2bf(v.y), h2 = f2bf(v.z), h3 = f2bf(v.w);
  short4 hi = {(short)h0, (short)h1, (short)h2, (short)h3};
  short4 lo = {(short)f2bf(v.x - bf2f(h0)), (short)f2bf(v.y - bf2f(h1)),
               (short)f2bf(v.z - bf2f(h2)), (short)f2bf(v.w - bf2f(h3))};
  *(short4*)&hhi[t * 4] = hi;
  *(short4*)&hlo[t * 4] = lo;
}

// ---------------- W -> W^T bf16  (wt[3][n][k]) ----------------
__global__ __launch_bounds__(256)
void transpose_w_kernel(const float* __restrict__ Wq, const float* __restrict__ Wk,
                        const float* __restrict__ Wv, u16* __restrict__ wt) {
  __shared__ float tile[64][65];
  const float* W = blockIdx.z == 0 ? Wq : blockIdx.z == 1 ? Wk : Wv;
  int k0 = blockIdx.x * 64, n0 = blockIdx.y * 64;
  int t = threadIdx.x;
  int lrow = t >> 4, lcol = (t & 15) * 4;
#pragma unroll
  for (int i = 0; i < 4; ++i) {
    float4 v = *(const float4*)&W[(size_t)(k0 + lrow + i * 16) * HID_ + n0 + lcol];
    tile[lrow + i * 16][lcol + 0] = v.x;
    tile[lrow + i * 16][lcol + 1] = v.y;
    tile[lrow + i * 16][lcol + 2] = v.z;
    tile[lrow + i * 16][lcol + 3] = v.w;
  }
  __syncthreads();
  int n = t >> 2, ks = (t & 3) * 16;
  u16 tmp[16];
#pragma unroll
  for (int j = 0; j < 16; ++j) tmp[j] = f2bf(tile[ks + j][n]);
  u16* dst = &wt[((size_t)blockIdx.z * 1024 + n0 + n) * 1024 + k0 + ks];
  ((uint4*)dst)[0] = ((uint4*)tmp)[0];
  ((uint4*)dst)[1] = ((uint4*)tmp)[1];
}

// ---------------- Fused QKV projection on MFMA ----------------
// C[m][n] = hs[m][:] . W^T[n][:],  n in [0,3072) = Q|K|V.  Split-A: C = A_hi*B + A_lo*B.
// Epilogue: Q/K -> bias+rope(+scale) bf16 [B,NH,S,HD]; V -> bias+bf16 [B,NH,HD,S].
__global__ __launch_bounds__(256)
void proj_gemm_kernel(const u16* __restrict__ Ah, const u16* __restrict__ Al,
                      const u16* __restrict__ Wt,
                      const float* __restrict__ bq, const float* __restrict__ bk,
                      const float* __restrict__ bv,
                      const float* __restrict__ ct, const float* __restrict__ st,
                      u16* __restrict__ qw, u16* __restrict__ kw, u16* __restrict__ vt) {
  __shared__ u16 sAh[128 * 64];
  __shared__ u16 sAl[128 * 64];
  __shared__ u16 sB[128 * 64];
  const int tid = threadIdx.x;
  const int wave = tid >> 6, lane = tid & 63;
  const int lr = lane & 15, lg = lane >> 4;

  int bid = blockIdx.x;
  int swz = (bid & 7) * 96 + (bid >> 3);
  const int gx = swz / 24, gy = swz % 24;
  const int m0 = gx * 128;
  const int ng0 = gy * 128;

  size_t aoff[4], boff[4];
  int c16[4];
#pragma unroll
  for (int i = 0; i < 4; ++i) {
    int c = i * 256 + tid;
    int row = c >> 3, ks = c & 7;
    int kph = (ks ^ (row & 7)) * 8;
    aoff[i] = (size_t)(m0 + row) * HID_ + kph;
    boff[i] = (size_t)(ng0 + row) * HID_ + kph;
    c16[i] = c * 16;
  }

  const int wr = (wave >> 1) * 64, wc = (wave & 1) * 64;
  int offA[4][2], offB[4][2];
#pragma unroll
  for (int f = 0; f < 4; ++f) {
    int ra = wr + f * 16 + lr;
    int rb = wc + f * 16 + lr;
#pragma unroll
    for (int kk = 0; kk < 2; ++kk) {
      offA[f][kk] = ra * 128 + (((kk * 4 + lg)) ^ (ra & 7)) * 16;
      offB[f][kk] = rb * 128 + (((kk * 4 + lg)) ^ (rb & 7)) * 16;
    }
  }

  f32x4 acc[4][4];
#pragma unroll
  for (int mf = 0; mf < 4; ++mf)
#pragma unroll
    for (int nf = 0; nf < 4; ++nf) acc[mf][nf] = (f32x4){0.f, 0.f, 0.f, 0.f};

  for (int k0 = 0; k0 < HID_; k0 += 64) {
    __syncthreads();
#pragma unroll
    for (int i = 0; i < 4; ++i) {
      gll16(Ah + aoff[i] + k0, (char*)sAh + c16[i]);
      gll16(Al + aoff[i] + k0, (char*)sAl + c16[i]);
      gll16(Wt + boff[i] + k0, (char*)sB + c16[i]);
    }
    __syncthreads();
#pragma unroll
    for (int kk = 0; kk < 2; ++kk) {
      bf16x8 a_h[4], a_l[4], bb[4];
#pragma unroll
      for (int f = 0; f < 4; ++f) {
        a_h[f] = *(const bf16x8*)((const char*)sAh + offA[f][kk]);
        a_l[f] = *(const bf16x8*)((const char*)sAl + offA[f][kk]);
        bb[f] = *(const bf16x8*)((const char*)sB + offB[f][kk]);
      }
#pragma unroll
      for (int mf = 0; mf < 4; ++mf)
#pragma unroll
        for (int nf = 0; nf < 4; ++nf) {
          acc[mf][nf] = __builtin_amdgcn_mfma_f32_16x16x32_bf16(a_h[mf], bb[nf], acc[mf][nf], 0, 0, 0);
          acc[mf][nf] = __builtin_amdgcn_mfma_f32_16x16x32_bf16(a_l[mf], bb[nf], acc[mf][nf], 0, 0, 0);
        }
    }
  }

  const int which = gy >> 3;
  const int colm = (gy & 7) * 128 + wc;
  const int h = colm >> 6;
  const float* bias = which == 0 ? bq : which == 1 ? bk : bv;
  const float scale = which == 0 ? 0.125f : 1.0f;

  if (which < 2) {
    u16* oh = which == 0 ? qw : kw;
#pragma unroll
    for (int mf = 0; mf < 4; ++mf) {
#pragma unroll
      for (int r = 0; r < 4; ++r) {
        int m = m0 + wr + mf * 16 + lg * 4 + r;
        int b = m >> 11, s = m & (S_ - 1);
        size_t rowb = (((size_t)b * NH_ + h) * S_ + s) * HD_;
#pragma unroll
        for (int nf = 0; nf < 2; ++nf) {
          int d = nf * 16 + lr;
          float x1 = acc[mf][nf][r] + bias[colm + d];
          float x2 = acc[mf][nf + 2][r] + bias[colm + d + 32];
          float cth = ct[s * 32 + d], sth = st[s * 32 + d];
          oh[rowb + d]      = f2bf((x1 * cth - x2 * sth) * scale);
          oh[rowb + d + 32] = f2bf((x2 * cth + x1 * sth) * scale);
        }
      }
    }
  } else {
#pragma unroll
    for (int mf = 0; mf < 4; ++mf) {
      int mB = m0 + wr + mf * 16 + lg * 4;
      int b = mB >> 11, s0 = mB & (S_ - 1);
#pragma unroll
      for (int nf = 0; nf < 4; ++nf) {
        int d = nf * 16 + lr;
        float bi = bias[colm + d];
        ushort4 pk;
        pk.x = f2bf(acc[mf][nf][0] + bi);
        pk.y = f2bf(acc[mf][nf][1] + bi);
        pk.z = f2bf(acc[mf][nf][2] + bi);
        pk.w = f2bf(acc[mf][nf][3] + bi);
        *(ushort4*)&vt[(((size_t)b * NH_ + h) * HD_ + d) * S_ + s0] = pk;
      }
    }
  }
}

// ---------------- Flash attention on MFMA (bf16, KVBLK=128) ----------
// LDS: K [128 kv][64 d] @0 (16K), V^T [64 d][128 kv] @16K, P [64 q][128 kv] @32K.
__global__ __launch_bounds__(256, 3)
void attn_mfma_kernel(const u16* __restrict__ qw, const u16* __restrict__ kw,
                      const u16* __restrict__ vt, const float* __restrict__ mask,
                      float* __restrict__ outp) {
  __shared__ __align__(16) char smem[49152];
  constexpr int VTB = 16384, PP = 32768;
  const int tid = threadIdx.x;
  const int wave = tid >> 6, lane = tid & 63;
  const int lr = lane & 15, lg = lane >> 4;

  // XCD-chunked: each XCD owns 4 heads x 32 q-tiles
  const int bid = blockIdx.x;
  const int idx = bid >> 3;
  const int bh = (bid & 7) * 4 + (idx >> 5);
  const int q0 = (idx & 31) * 64;
  const int b = bh >> 4, h = bh & 15;
  const size_t hb = (size_t)bh * S_ * HD_;

  // Q fragments: A row = lr, k = t*32 + lg*8
  bf16x8 aq[2];
  {
    size_t base = hb + (size_t)(q0 + wave * 16 + lr) * HD_ + lg * 8;
    aq[0] = *(const bf16x8*)&qw[base];
    aq[1] = *(const bf16x8*)&qw[base + 32];
  }

  f32x4 O[4];
  float mrun[4], lrun[4];
#pragma unroll
  for (int r = 0; r < 4; ++r) {
    O[r] = (f32x4){0.f, 0.f, 0.f, 0.f};
    mrun[r] = -INFINITY;
    lrun[r] = 0.f;
  }

  // staging offsets (global source pre-swizzled, LDS dest linear)
  size_t kgo[4], vgo[4];
  int klo_[4], vlo_[4];
#pragma unroll
  for (int i = 0; i < 4; ++i) {
    int a = i * 4096 + tid * 16;
    {
      int row = a >> 7, seg = (a >> 4) & 7;
      kgo[i] = (size_t)row * HD_ + ((seg ^ (row & 7)) * 8);
      klo_[i] = a;
    }
    {
      int row = a >> 8, seg = (a >> 4) & 15;
      int sg = (seg & 8) | ((seg & 7) ^ (row & 7));
      vgo[i] = (size_t)row * S_ + sg * 8;
      vlo_[i] = VTB + a;
    }
  }

  for (int k0 = 0; k0 < S_; k0 += 128) {
    __syncthreads();
#pragma unroll
    for (int i = 0; i < 4; ++i) {
      gll16(kw + hb + kgo[i] + (size_t)k0 * HD_, smem + klo_[i]);
      gll16(vt + hb + vgo[i] + k0, smem + vlo_[i]);
    }
    __syncthreads();

    // S = Q K^T : 16 q-rows x 128 kv per wave
    f32x4 sc[8];
#pragma unroll
    for (int c = 0; c < 8; ++c) sc[c] = (f32x4){0.f, 0.f, 0.f, 0.f};
#pragma unroll
    for (int t = 0; t < 2; ++t) {
#pragma unroll
      for (int c = 0; c < 8; ++c) {
        int n = c * 16 + lr;
        int off = (n << 7) + ((t * 64 + lg * 16) ^ ((n & 7) << 4));
        bf16x8 bk8 = *(const bf16x8*)(smem + off);
        sc[c] = __builtin_amdgcn_mfma_f32_16x16x32_bf16(aq[t], bk8, sc[c], 0, 0, 0);
      }
    }

    float mk[8];
#pragma unroll
    for (int c = 0; c < 8; ++c) mk[c] = mask[(size_t)b * S_ + k0 + c * 16 + lr];

    // online softmax; row r at D row = lg*4+r, cols c*16+lr
#pragma unroll
    for (int r = 0; r < 4; ++r) {
      float sv[8];
      float mx = -INFINITY;
#pragma unroll
      for (int c = 0; c < 8; ++c) { sv[c] = sc[c][r] + mk[c]; mx = fmaxf(mx, sv[c]); }
      mx = fmaxf(mx, __shfl_xor(mx, 1));
      mx = fmaxf(mx, __shfl_xor(mx, 2));
      mx = fmaxf(mx, __shfl_xor(mx, 4));
      mx = fmaxf(mx, __shfl_xor(mx, 8));
      if (mx > mrun[r]) {
        float corr = __expf(mrun[r] - mx);
        mrun[r] = mx;
        lrun[r] *= corr;
        O[0][r] *= corr; O[1][r] *= corr; O[2][r] *= corr; O[3][r] *= corr;
      }
      int prow = wave * 16 + lg * 4 + r;
      int pswz = (prow & 7) << 4;
      float rs = 0.f;
#pragma unroll
      for (int c = 0; c < 8; ++c) {
        u16 pb = f2bf(__expf(sv[c] - mrun[r]));
        rs += bf2f(pb);
        *(u16*)(smem + PP + ((prow * 256 + (c * 16 + lr) * 2) ^ pswz)) = pb;
      }
      rs += __shfl_xor(rs, 1);
      rs += __shfl_xor(rs, 2);
      rs += __shfl_xor(rs, 4);
      rs += __shfl_xor(rs, 8);
      lrun[r] += rs;
    }

    // O += P V : A = P rows (m=lr), k = kv; B = V^T (n=d rows)
#pragma unroll
    for (int kt = 0; kt < 4; ++kt) {
      int prow = wave * 16 + lr;
      bf16x8 ap = *(const bf16x8*)(smem + PP +
                   ((prow * 256 + (kt * 32 + lg * 8) * 2) ^ ((prow & 7) << 4)));
#pragma unroll
      for (int dt = 0; dt < 4; ++dt) {
        int n = dt * 16 + lr;
        int off = VTB + (n << 8) + ((kt * 64 + lg * 16) ^ ((n & 7) << 4));
        bf16x8 bv8 = *(const bf16x8*)(smem + off);
        O[dt] = __builtin_amdgcn_mfma_f32_16x16x32_bf16(ap, bv8, O[dt], 0, 0, 0);
      }
    }
  }

  // epilogue: normalize, write ctx [B, S, HID] fp32
#pragma unroll
  for (int r = 0; r < 4; ++r) {
    float inv = 1.0f / lrun[r];
    int s = q0 + wave * 16 + lg * 4 + r;
    size_t rowb = ((size_t)b * S_ + s) * HID_ + h * HD_;
#pragma unroll
    for (int dt = 0; dt < 4; ++dt)
      outp[rowb + dt * 16 + lr] = O[dt][r] * inv;
  }
}

}  // namespace

extern "C" void kernel_launch(void* const* d_in, const int* in_sizes, int n_in,
                              void* d_out, int out_size, void* d_ws, size_t ws_size,
                              hipStream_t stream) {
  const float* hs   = (const float*)d_in[0];
  const float* mask = (const float*)d_in[1];
  const float* Wq   = (const float*)d_in[2];
  const float* bq   = (const float*)d_in[3];
  const float* Wk   = (const float*)d_in[4];
  const float* bk   = (const float*)d_in[5];
  const float* Wv   = (const float*)d_in[6];
  const float* bv   = (const float*)d_in[7];

  u16* qw  = (u16*)d_ws;                 // [B,NH,S,HD] bf16 (rope+scale)
  u16* kw  = qw + QSZ;                   // [B,NH,S,HD] bf16 (rope)
  u16* vt  = kw + QSZ;                   // [B,NH,HD,S] bf16
  u16* hhi = vt + QSZ;                   // [M, HID]
  u16* hlo = hhi + (size_t)M_ * HID_;
  u16* wt  = hlo + (size_t)M_ * HID_;    // [3][1024][1024] transposed bf16
  float* ct = (float*)(wt + (size_t)3 * 1024 * 1024);
  float* st = ct + TBL;

  rope_table_kernel<<<TBL / 256, 256, 0, stream>>>(ct, st);
  convert_hs_kernel<<<(M_ * HID_) / 1024, 256, 0, stream>>>(hs, hhi, hlo);
  transpose_w_kernel<<<dim3(16, 16, 3), 256, 0, stream>>>(Wq, Wk, Wv, wt);

  proj_gemm_kernel<<<768, 256, 0, stream>>>(hhi, hlo, wt, bq, bk, bv, ct, st, qw, kw, vt);

  attn_mfma_kernel<<<1024, 256, 0, stream>>>(qw, kw, vt, mask, (float*)d_out);
}

// Round 5
// 136.230 us; speedup vs baseline: 6.8300x; 1.3824x over previous
//
#include <hip/hip_runtime.h>
#include <math.h>

namespace {
constexpr int B_ = 2, S_ = 2048, HID_ = 1024, NH_ = 16, HD_ = 64;
constexpr int M_ = B_ * S_;                 // 4096 rows
constexpr int QSZ = B_ * NH_ * S_ * HD_;    // 4194304 elements per tensor
constexpr int TBL = S_ * (HD_ / 2);         // 65536 cos/sin entries

typedef float f32x4 __attribute__((ext_vector_type(4)));
typedef __bf16 bf16x8 __attribute__((ext_vector_type(8)));
typedef unsigned int u32x4 __attribute__((ext_vector_type(4)));
typedef unsigned short u16;

__device__ inline u16 f2bf(float x) {
  unsigned int u = __float_as_uint(x);
  return (u16)((u + 0x7fffu + ((u >> 16) & 1u)) >> 16);
}
__device__ inline float bf2f(u16 h) {
  return __uint_as_float(((unsigned int)h) << 16);
}

typedef __attribute__((address_space(1))) const unsigned int as1_u32;
typedef __attribute__((address_space(3))) unsigned int as3_u32;
__device__ __forceinline__ void gll16(const void* g, void* l) {
  __builtin_amdgcn_global_load_lds((as1_u32*)g, (as3_u32*)l, 16, 0, 0);
}

// gfx950 cross-lane row swaps (VALU, no LDS pipe)
__device__ __forceinline__ void swap32(unsigned int& a, unsigned int& b) {
  asm("v_permlane32_swap_b32 %0, %1" : "+v"(a), "+v"(b));
}
__device__ __forceinline__ void swap16(unsigned int& a, unsigned int& b) {
  asm("v_permlane16_swap_b32 %0, %1" : "+v"(a), "+v"(b));
}
__device__ __forceinline__ unsigned int cvtpk(float lo, float hi) {
  unsigned int r;
  asm("v_cvt_pk_bf16_f32 %0, %1, %2" : "=v"(r) : "v"(lo), "v"(hi));
  return r;
}

// ---------------- RoPE cos/sin table ----------------
__global__ void rope_table_kernel(float* __restrict__ ct, float* __restrict__ st) {
  int t = blockIdx.x * blockDim.x + threadIdx.x;
  if (t >= TBL) return;
  int s = t >> 5, i = t & 31;
  float inv = 1.0f / powf(10000.0f, (float)(2 * i) / (float)HD_);
  float ang = (float)s * inv;
  double a = (double)ang;
  ct[t] = (float)cos(a);
  st[t] = (float)sin(a);
}

// ---------------- hs -> bf16 hi/lo split ----------------
__global__ __launch_bounds__(256)
void convert_hs_kernel(const float* __restrict__ hs, u16* __restrict__ hhi, u16* __restrict__ hlo) {
  size_t t = (size_t)blockIdx.x * 256 + threadIdx.x;
  float4 v = *(const float4*)&hs[t * 4];
  u16 h0 = f2bf(v.x), h1 = f2bf(v.y), h2 = f2bf(v.z), h3 = f2bf(v.w);
  short4 hi = {(short)h0, (short)h1, (short)h2, (short)h3};
  short4 lo = {(short)f2bf(v.x - bf2f(h0)), (short)f2bf(v.y - bf2f(h1)),
               (short)f2bf(v.z - bf2f(h2)), (short)f2bf(v.w - bf2f(h3))};
  *(short4*)&hhi[t * 4] = hi;
  *(short4*)&hlo[t * 4] = lo;
}

// ---------------- W -> W^T bf16  (wt[3][n][k]) ----------------
__global__ __launch_bounds__(256)
void transpose_w_kernel(const float* __restrict__ Wq, const float* __restrict__ Wk,
                        const float* __restrict__ Wv, u16* __restrict__ wt) {
  __shared__ float tile[64][65];
  const float* W = blockIdx.z == 0 ? Wq : blockIdx.z == 1 ? Wk : Wv;
  int k0 = blockIdx.x * 64, n0 = blockIdx.y * 64;
  int t = threadIdx.x;
  int lrow = t >> 4, lcol = (t & 15) * 4;
#pragma unroll
  for (int i = 0; i < 4; ++i) {
    float4 v = *(const float4*)&W[(size_t)(k0 + lrow + i * 16) * HID_ + n0 + lcol];
    tile[lrow + i * 16][lcol + 0] = v.x;
    tile[lrow + i * 16][lcol + 1] = v.y;
    tile[lrow + i * 16][lcol + 2] = v.z;
    tile[lrow + i * 16][lcol + 3] = v.w;
  }
  __syncthreads();
  int n = t >> 2, ks = (t & 3) * 16;
  u16 tmp[16];
#pragma unroll
  for (int j = 0; j < 16; ++j) tmp[j] = f2bf(tile[ks + j][n]);
  u16* dst = &wt[((size_t)blockIdx.z * 1024 + n0 + n) * 1024 + k0 + ks];
  ((uint4*)dst)[0] = ((uint4*)tmp)[0];
  ((uint4*)dst)[1] = ((uint4*)tmp)[1];
}

// ---------------- Fused QKV projection on MFMA ----------------
__global__ __launch_bounds__(256)
void proj_gemm_kernel(const u16* __restrict__ Ah, const u16* __restrict__ Al,
                      const u16* __restrict__ Wt,
                      const float* __restrict__ bq, const float* __restrict__ bk,
                      const float* __restrict__ bv,
                      const float* __restrict__ ct, const float* __restrict__ st,
                      u16* __restrict__ qw, u16* __restrict__ kw, u16* __restrict__ vt) {
  __shared__ u16 sAh[128 * 64];
  __shared__ u16 sAl[128 * 64];
  __shared__ u16 sB[128 * 64];
  const int tid = threadIdx.x;
  const int wave = tid >> 6, lane = tid & 63;
  const int lr = lane & 15, lg = lane >> 4;

  int bid = blockIdx.x;
  int swz = (bid & 7) * 96 + (bid >> 3);
  const int gx = swz / 24, gy = swz % 24;
  const int m0 = gx * 128;
  const int ng0 = gy * 128;

  size_t aoff[4], boff[4];
  int c16[4];
#pragma unroll
  for (int i = 0; i < 4; ++i) {
    int c = i * 256 + tid;
    int row = c >> 3, ks = c & 7;
    int kph = (ks ^ (row & 7)) * 8;
    aoff[i] = (size_t)(m0 + row) * HID_ + kph;
    boff[i] = (size_t)(ng0 + row) * HID_ + kph;
    c16[i] = c * 16;
  }

  const int wr = (wave >> 1) * 64, wc = (wave & 1) * 64;
  int offA[4][2], offB[4][2];
#pragma unroll
  for (int f = 0; f < 4; ++f) {
    int ra = wr + f * 16 + lr;
    int rb = wc + f * 16 + lr;
#pragma unroll
    for (int kk = 0; kk < 2; ++kk) {
      offA[f][kk] = ra * 128 + (((kk * 4 + lg)) ^ (ra & 7)) * 16;
      offB[f][kk] = rb * 128 + (((kk * 4 + lg)) ^ (rb & 7)) * 16;
    }
  }

  f32x4 acc[4][4];
#pragma unroll
  for (int mf = 0; mf < 4; ++mf)
#pragma unroll
    for (int nf = 0; nf < 4; ++nf) acc[mf][nf] = (f32x4){0.f, 0.f, 0.f, 0.f};

  for (int k0 = 0; k0 < HID_; k0 += 64) {
    __syncthreads();
#pragma unroll
    for (int i = 0; i < 4; ++i) {
      gll16(Ah + aoff[i] + k0, (char*)sAh + c16[i]);
      gll16(Al + aoff[i] + k0, (char*)sAl + c16[i]);
      gll16(Wt + boff[i] + k0, (char*)sB + c16[i]);
    }
    __syncthreads();
#pragma unroll
    for (int kk = 0; kk < 2; ++kk) {
      bf16x8 a_h[4], a_l[4], bb[4];
#pragma unroll
      for (int f = 0; f < 4; ++f) {
        a_h[f] = *(const bf16x8*)((const char*)sAh + offA[f][kk]);
        a_l[f] = *(const bf16x8*)((const char*)sAl + offA[f][kk]);
        bb[f] = *(const bf16x8*)((const char*)sB + offB[f][kk]);
      }
#pragma unroll
      for (int mf = 0; mf < 4; ++mf)
#pragma unroll
        for (int nf = 0; nf < 4; ++nf) {
          acc[mf][nf] = __builtin_amdgcn_mfma_f32_16x16x32_bf16(a_h[mf], bb[nf], acc[mf][nf], 0, 0, 0);
          acc[mf][nf] = __builtin_amdgcn_mfma_f32_16x16x32_bf16(a_l[mf], bb[nf], acc[mf][nf], 0, 0, 0);
        }
    }
  }

  const int which = gy >> 3;
  const int colm = (gy & 7) * 128 + wc;
  const int h = colm >> 6;
  const float* bias = which == 0 ? bq : which == 1 ? bk : bv;
  const float scale = which == 0 ? 0.125f : 1.0f;

  if (which < 2) {
    u16* oh = which == 0 ? qw : kw;
#pragma unroll
    for (int mf = 0; mf < 4; ++mf) {
#pragma unroll
      for (int r = 0; r < 4; ++r) {
        int m = m0 + wr + mf * 16 + lg * 4 + r;
        int b = m >> 11, s = m & (S_ - 1);
        size_t rowb = (((size_t)b * NH_ + h) * S_ + s) * HD_;
#pragma unroll
        for (int nf = 0; nf < 2; ++nf) {
          int d = nf * 16 + lr;
          float x1 = acc[mf][nf][r] + bias[colm + d];
          float x2 = acc[mf][nf + 2][r] + bias[colm + d + 32];
          float cth = ct[s * 32 + d], sth = st[s * 32 + d];
          oh[rowb + d]      = f2bf((x1 * cth - x2 * sth) * scale);
          oh[rowb + d + 32] = f2bf((x2 * cth + x1 * sth) * scale);
        }
      }
    }
  } else {
#pragma unroll
    for (int mf = 0; mf < 4; ++mf) {
      int mB = m0 + wr + mf * 16 + lg * 4;
      int b = mB >> 11, s0 = mB & (S_ - 1);
#pragma unroll
      for (int nf = 0; nf < 4; ++nf) {
        int d = nf * 16 + lr;
        float bi = bias[colm + d];
        ushort4 pk;
        pk.x = f2bf(acc[mf][nf][0] + bi);
        pk.y = f2bf(acc[mf][nf][1] + bi);
        pk.z = f2bf(acc[mf][nf][2] + bi);
        pk.w = f2bf(acc[mf][nf][3] + bi);
        *(ushort4*)&vt[(((size_t)b * NH_ + h) * HD_ + d) * S_ + s0] = pk;
      }
    }
  }
}

// ---------------- Flash attention: swapped QK^T, in-register P via permlane ----
// LDS: K [128 kv][64 d] @0 (16K), V^T [64 d][128 kv] @16K (16K), mask [2048 f32] @32K (8K).
// 4 waves x 32 q-rows (2 q-blocks of 16); lane (lg,lr) owns q-row lr of each q-block.
__global__ __launch_bounds__(256, 2)
void attn_mfma_kernel(const u16* __restrict__ qw, const u16* __restrict__ kw,
                      const u16* __restrict__ vt, const float* __restrict__ mask,
                      float* __restrict__ outp) {
  __shared__ __align__(16) char smem[40960];
  constexpr int VTB = 16384, MS = 32768;
  const int tid = threadIdx.x;
  const int wave = tid >> 6, lane = tid & 63;
  const int lr = lane & 15, lg = lane >> 4;

  // XCD-chunked: 512 blocks, each XCD owns 4 heads x 16 q-tiles
  const int bid = blockIdx.x;
  const int idx = bid >> 3;
  const int bh = (bid & 7) * 4 + (idx >> 4);
  const int q0 = (idx & 15) * 128;
  const int b = bh >> 4, h = bh & 15;
  const size_t hb = (size_t)bh * S_ * HD_;

  // stage mask row (2048 f32 = 8KB) once
  gll16(mask + (size_t)b * S_ + tid * 4, smem + MS + tid * 16);
  gll16(mask + (size_t)b * S_ + 1024 + tid * 4, smem + MS + 4096 + tid * 16);

  // Q as B-fragments: lane holds Q[q = q0 + wave*32 + qb*16 + lr][d = t*32 + lg*8 + j]
  bf16x8 aq[2][2];
#pragma unroll
  for (int qb = 0; qb < 2; ++qb) {
    size_t base = hb + (size_t)(q0 + wave * 32 + qb * 16 + lr) * HD_ + lg * 8;
    aq[qb][0] = *(const bf16x8*)&qw[base];
    aq[qb][1] = *(const bf16x8*)&qw[base + 32];
  }

  f32x4 O[2][4];
  float mrun[2], lrun[2];
#pragma unroll
  for (int qb = 0; qb < 2; ++qb) {
    mrun[qb] = -INFINITY;
    lrun[qb] = 0.f;
#pragma unroll
    for (int dt = 0; dt < 4; ++dt) O[qb][dt] = (f32x4){0.f, 0.f, 0.f, 0.f};
  }

  // staging offsets (global source pre-swizzled, LDS dest linear)
  size_t kgo[4], vgo[4];
  int klo_[4], vlo_[4];
#pragma unroll
  for (int i = 0; i < 4; ++i) {
    int a = i * 4096 + tid * 16;
    {
      int row = a >> 7, seg = (a >> 4) & 7;
      kgo[i] = (size_t)row * HD_ + ((seg ^ (row & 7)) * 8);
      klo_[i] = a;
    }
    {
      int row = a >> 8, seg = (a >> 4) & 15;
      int sg = (seg & 8) | ((seg & 7) ^ (row & 7));
      vgo[i] = (size_t)row * S_ + sg * 8;
      vlo_[i] = VTB + a;
    }
  }

  const int sw = (lr & 7) << 4;

  for (int k0 = 0; k0 < S_; k0 += 128) {
    __syncthreads();
#pragma unroll
    for (int i = 0; i < 4; ++i) {
      gll16(kw + hb + kgo[i] + (size_t)k0 * HD_, smem + klo_[i]);
      gll16(vt + hb + vgo[i] + k0, smem + vlo_[i]);
    }
    __syncthreads();

    // S^T = K Q^T per kv-tile c: lane gets S[q=lr][kv = c*16 + lg*4 + r]
    f32x4 sc[2][8];
#pragma unroll
    for (int qb = 0; qb < 2; ++qb)
#pragma unroll
      for (int c = 0; c < 8; ++c) sc[qb][c] = (f32x4){0.f, 0.f, 0.f, 0.f};
#pragma unroll
    for (int t = 0; t < 2; ++t) {
#pragma unroll
      for (int c = 0; c < 8; ++c) {
        int off = ((c * 16 + lr) << 7) + ((t * 64 + lg * 16) ^ sw);
        bf16x8 kf = *(const bf16x8*)(smem + off);
        sc[0][c] = __builtin_amdgcn_mfma_f32_16x16x32_bf16(kf, aq[0][t], sc[0][c], 0, 0, 0);
        sc[1][c] = __builtin_amdgcn_mfma_f32_16x16x32_bf16(kf, aq[1][t], sc[1][c], 0, 0, 0);
      }
    }

    // mask (broadcast LDS reads, 4 consecutive floats per c)
    f32x4 mk[8];
#pragma unroll
    for (int c = 0; c < 8; ++c)
      mk[c] = *(const f32x4*)(smem + MS + (k0 + c * 16 + lg * 4) * 4);

    // softmax + in-register P-fragment build
    bf16x8 pf[2][4];
#pragma unroll
    for (int qb = 0; qb < 2; ++qb) {
      float mx = -INFINITY;
#pragma unroll
      for (int c = 0; c < 8; ++c) {
        sc[qb][c] += mk[c];
#pragma unroll
        for (int r = 0; r < 4; ++r) mx = fmaxf(mx, sc[qb][c][r]);
      }
      mx = fmaxf(mx, __shfl_xor(mx, 16));
      mx = fmaxf(mx, __shfl_xor(mx, 32));
      if (mx > mrun[qb]) {
        float corr = __expf(mrun[qb] - mx);
        mrun[qb] = mx;
        lrun[qb] *= corr;
#pragma unroll
        for (int dt = 0; dt < 4; ++dt) O[qb][dt] *= corr;
      }
      float rs = 0.f;
#pragma unroll
      for (int c = 0; c < 8; ++c) {
#pragma unroll
        for (int r = 0; r < 4; ++r) {
          float p = __expf(sc[qb][c][r] - mrun[qb]);
          sc[qb][c][r] = p;
          rs += p;
        }
      }
      rs += __shfl_xor(rs, 16);
      rs += __shfl_xor(rs, 32);
      lrun[qb] += rs;

      // pack P (bf16 pairs) then redistribute: lane lg2 gets kv = kt*32 + lg2*8 + j
#pragma unroll
      for (int kt = 0; kt < 4; ++kt) {
        unsigned int x0 = cvtpk(sc[qb][2 * kt][0], sc[qb][2 * kt][1]);
        unsigned int x1 = cvtpk(sc[qb][2 * kt + 1][0], sc[qb][2 * kt + 1][1]);
        unsigned int y0 = cvtpk(sc[qb][2 * kt][2], sc[qb][2 * kt][3]);
        unsigned int y1 = cvtpk(sc[qb][2 * kt + 1][2], sc[qb][2 * kt + 1][3]);
        swap32(x0, x1);
        swap16(x0, x1);  // x0 = j0-1, x1 = j4-5
        swap32(y0, y1);
        swap16(y0, y1);  // y0 = j2-3, y1 = j6-7
        u32x4 f = {x0, y0, x1, y1};
        pf[qb][kt] = *(bf16x8*)&f;
      }
    }

    // O^T += V^T P^T : A = V^T (m = d), B = P^T (n = q)
#pragma unroll
    for (int kt = 0; kt < 4; ++kt) {
#pragma unroll
      for (int dt = 0; dt < 4; ++dt) {
        int off = VTB + ((dt * 16 + lr) << 8) + ((kt * 64 + lg * 16) ^ sw);
        bf16x8 vf = *(const bf16x8*)(smem + off);
        O[0][dt] = __builtin_amdgcn_mfma_f32_16x16x32_bf16(vf, pf[0][kt], O[0][dt], 0, 0, 0);
        O[1][dt] = __builtin_amdgcn_mfma_f32_16x16x32_bf16(vf, pf[1][kt], O[1][dt], 0, 0, 0);
      }
    }
  }

  // epilogue: lane owns q-row (q0 + wave*32 + qb*16 + lr), d = dt*16 + lg*4 + r
#pragma unroll
  for (int qb = 0; qb < 2; ++qb) {
    float inv = 1.0f / lrun[qb];
    int s = q0 + wave * 32 + qb * 16 + lr;
    size_t rowb = ((size_t)b * S_ + s) * HID_ + h * HD_;
#pragma unroll
    for (int dt = 0; dt < 4; ++dt) {
      float4 r;
      r.x = O[qb][dt][0] * inv;
      r.y = O[qb][dt][1] * inv;
      r.z = O[qb][dt][2] * inv;
      r.w = O[qb][dt][3] * inv;
      *(float4*)&outp[rowb + dt * 16 + lg * 4] = r;
    }
  }
}

}  // namespace

extern "C" void kernel_launch(void* const* d_in, const int* in_sizes, int n_in,
                              void* d_out, int out_size, void* d_ws, size_t ws_size,
                              hipStream_t stream) {
  const float* hs   = (const float*)d_in[0];
  const float* mask = (const float*)d_in[1];
  const float* Wq   = (const float*)d_in[2];
  const float* bq   = (const float*)d_in[3];
  const float* Wk   = (const float*)d_in[4];
  const float* bk   = (const float*)d_in[5];
  const float* Wv   = (const float*)d_in[6];
  const float* bv   = (const float*)d_in[7];

  u16* qw  = (u16*)d_ws;                 // [B,NH,S,HD] bf16 (rope+scale)
  u16* kw  = qw + QSZ;                   // [B,NH,S,HD] bf16 (rope)
  u16* vt  = kw + QSZ;                   // [B,NH,HD,S] bf16
  u16* hhi = vt + QSZ;                   // [M, HID]
  u16* hlo = hhi + (size_t)M_ * HID_;
  u16* wt  = hlo + (size_t)M_ * HID_;    // [3][1024][1024] transposed bf16
  float* ct = (float*)(wt + (size_t)3 * 1024 * 1024);
  float* st = ct + TBL;

  rope_table_kernel<<<TBL / 256, 256, 0, stream>>>(ct, st);
  convert_hs_kernel<<<(M_ * HID_) / 1024, 256, 0, stream>>>(hs, hhi, hlo);
  transpose_w_kernel<<<dim3(16, 16, 3), 256, 0, stream>>>(Wq, Wk, Wv, wt);

  proj_gemm_kernel<<<768, 256, 0, stream>>>(hhi, hlo, wt, bq, bk, bv, ct, st, qw, kw, vt);

  attn_mfma_kernel<<<512, 256, 0, stream>>>(qw, kw, vt, mask, (float*)d_out);
}

// Round 7
// 113.903 us; speedup vs baseline: 8.1688x; 1.1960x over previous
//
#include <hip/hip_runtime.h>
#include <math.h>

namespace {
constexpr int B_ = 2, S_ = 2048, HID_ = 1024, NH_ = 16, HD_ = 64;
constexpr int M_ = B_ * S_;                 // 4096 rows
constexpr int QSZ = B_ * NH_ * S_ * HD_;    // 4194304 elements per tensor
constexpr int TBL = S_ * (HD_ / 2);         // 65536 cos/sin entries
constexpr float LOG2E = 1.4426950408889634f;

typedef float f32x4 __attribute__((ext_vector_type(4)));
typedef __bf16 bf16x8 __attribute__((ext_vector_type(8)));
typedef unsigned int u32x4 __attribute__((ext_vector_type(4)));
typedef unsigned short u16;

__device__ inline u16 f2bf(float x) {
  unsigned int u = __float_as_uint(x);
  return (u16)((u + 0x7fffu + ((u >> 16) & 1u)) >> 16);
}
__device__ inline float bf2f(u16 h) {
  return __uint_as_float(((unsigned int)h) << 16);
}

typedef __attribute__((address_space(1))) const unsigned int as1_u32;
typedef __attribute__((address_space(3))) unsigned int as3_u32;
__device__ __forceinline__ void gll16(const void* g, void* l) {
  __builtin_amdgcn_global_load_lds((as1_u32*)g, (as3_u32*)l, 16, 0, 0);
}

// gfx950 cross-lane row swaps (VALU, no LDS pipe)
__device__ __forceinline__ void swap32(unsigned int& a, unsigned int& b) {
  asm("v_permlane32_swap_b32 %0, %1" : "+v"(a), "+v"(b));
}
__device__ __forceinline__ void swap16(unsigned int& a, unsigned int& b) {
  asm("v_permlane16_swap_b32 %0, %1" : "+v"(a), "+v"(b));
}
__device__ __forceinline__ unsigned int cvtpk(float lo, float hi) {
  unsigned int r;
  asm("v_cvt_pk_bf16_f32 %0, %1, %2" : "=v"(r) : "v"(lo), "v"(hi));
  return r;
}

// ---------------- RoPE cos/sin table ----------------
__global__ void rope_table_kernel(float* __restrict__ ct, float* __restrict__ st) {
  int t = blockIdx.x * blockDim.x + threadIdx.x;
  if (t >= TBL) return;
  int s = t >> 5, i = t & 31;
  float inv = 1.0f / powf(10000.0f, (float)(2 * i) / (float)HD_);
  float ang = (float)s * inv;
  double a = (double)ang;
  ct[t] = (float)cos(a);
  st[t] = (float)sin(a);
}

// ---------------- hs -> bf16 ----------------
__global__ __launch_bounds__(256)
void convert_hs_kernel(const float* __restrict__ hs, u16* __restrict__ hh) {
  size_t t = (size_t)blockIdx.x * 256 + threadIdx.x;
  float4 v = *(const float4*)&hs[t * 4];
  short4 hi = {(short)f2bf(v.x), (short)f2bf(v.y), (short)f2bf(v.z), (short)f2bf(v.w)};
  *(short4*)&hh[t * 4] = hi;
}

// ---------------- W -> W^T bf16  (wt[3][n][k]) ----------------
__global__ __launch_bounds__(256)
void transpose_w_kernel(const float* __restrict__ Wq, const float* __restrict__ Wk,
                        const float* __restrict__ Wv, u16* __restrict__ wt) {
  __shared__ float tile[64][65];
  const float* W = blockIdx.z == 0 ? Wq : blockIdx.z == 1 ? Wk : Wv;
  int k0 = blockIdx.x * 64, n0 = blockIdx.y * 64;
  int t = threadIdx.x;
  int lrow = t >> 4, lcol = (t & 15) * 4;
#pragma unroll
  for (int i = 0; i < 4; ++i) {
    float4 v = *(const float4*)&W[(size_t)(k0 + lrow + i * 16) * HID_ + n0 + lcol];
    tile[lrow + i * 16][lcol + 0] = v.x;
    tile[lrow + i * 16][lcol + 1] = v.y;
    tile[lrow + i * 16][lcol + 2] = v.z;
    tile[lrow + i * 16][lcol + 3] = v.w;
  }
  __syncthreads();
  int n = t >> 2, ks = (t & 3) * 16;
  u16 tmp[16];
#pragma unroll
  for (int j = 0; j < 16; ++j) tmp[j] = f2bf(tile[ks + j][n]);
  u16* dst = &wt[((size_t)blockIdx.z * 1024 + n0 + n) * 1024 + k0 + ks];
  ((uint4*)dst)[0] = ((uint4*)tmp)[0];
  ((uint4*)dst)[1] = ((uint4*)tmp)[1];
}

// ---------------- Fused QKV projection on MFMA (plain bf16 A) ----------------
__global__ __launch_bounds__(256)
void proj_gemm_kernel(const u16* __restrict__ Ah, const u16* __restrict__ Wt,
                      const float* __restrict__ bq, const float* __restrict__ bk,
                      const float* __restrict__ bv,
                      const float* __restrict__ ct, const float* __restrict__ st,
                      u16* __restrict__ qw, u16* __restrict__ kw, u16* __restrict__ vt) {
  __shared__ u16 sAh[128 * 64];
  __shared__ u16 sB[128 * 64];
  const int tid = threadIdx.x;
  const int wave = tid >> 6, lane = tid & 63;
  const int lr = lane & 15, lg = lane >> 4;

  int bid = blockIdx.x;
  int swz = (bid & 7) * 96 + (bid >> 3);
  const int gx = swz / 24, gy = swz % 24;
  const int m0 = gx * 128;
  const int ng0 = gy * 128;

  size_t aoff[4], boff[4];
  int c16[4];
#pragma unroll
  for (int i = 0; i < 4; ++i) {
    int c = i * 256 + tid;
    int row = c >> 3, ks = c & 7;
    int kph = (ks ^ (row & 7)) * 8;
    aoff[i] = (size_t)(m0 + row) * HID_ + kph;
    boff[i] = (size_t)(ng0 + row) * HID_ + kph;
    c16[i] = c * 16;
  }

  const int wr = (wave >> 1) * 64, wc = (wave & 1) * 64;
  int offA[4][2], offB[4][2];
#pragma unroll
  for (int f = 0; f < 4; ++f) {
    int ra = wr + f * 16 + lr;
    int rb = wc + f * 16 + lr;
#pragma unroll
    for (int kk = 0; kk < 2; ++kk) {
      offA[f][kk] = ra * 128 + (((kk * 4 + lg)) ^ (ra & 7)) * 16;
      offB[f][kk] = rb * 128 + (((kk * 4 + lg)) ^ (rb & 7)) * 16;
    }
  }

  f32x4 acc[4][4];
#pragma unroll
  for (int mf = 0; mf < 4; ++mf)
#pragma unroll
    for (int nf = 0; nf < 4; ++nf) acc[mf][nf] = (f32x4){0.f, 0.f, 0.f, 0.f};

  for (int k0 = 0; k0 < HID_; k0 += 64) {
    __syncthreads();
#pragma unroll
    for (int i = 0; i < 4; ++i) {
      gll16(Ah + aoff[i] + k0, (char*)sAh + c16[i]);
      gll16(Wt + boff[i] + k0, (char*)sB + c16[i]);
    }
    __syncthreads();
#pragma unroll
    for (int kk = 0; kk < 2; ++kk) {
      bf16x8 a_h[4], bb[4];
#pragma unroll
      for (int f = 0; f < 4; ++f) {
        a_h[f] = *(const bf16x8*)((const char*)sAh + offA[f][kk]);
        bb[f] = *(const bf16x8*)((const char*)sB + offB[f][kk]);
      }
      __builtin_amdgcn_s_setprio(1);
#pragma unroll
      for (int mf = 0; mf < 4; ++mf)
#pragma unroll
        for (int nf = 0; nf < 4; ++nf)
          acc[mf][nf] = __builtin_amdgcn_mfma_f32_16x16x32_bf16(a_h[mf], bb[nf], acc[mf][nf], 0, 0, 0);
      __builtin_amdgcn_s_setprio(0);
    }
  }

  const int which = gy >> 3;
  const int colm = (gy & 7) * 128 + wc;
  const int h = colm >> 6;
  const float* bias = which == 0 ? bq : which == 1 ? bk : bv;
  // Q folds HD^-0.5 AND log2(e) for the exp2-domain softmax
  const float scale = which == 0 ? 0.125f * LOG2E : 1.0f;

  if (which < 2) {
    u16* oh = which == 0 ? qw : kw;
#pragma unroll
    for (int mf = 0; mf < 4; ++mf) {
#pragma unroll
      for (int r = 0; r < 4; ++r) {
        int m = m0 + wr + mf * 16 + lg * 4 + r;
        int b = m >> 11, s = m & (S_ - 1);
        size_t rowb = (((size_t)b * NH_ + h) * S_ + s) * HD_;
#pragma unroll
        for (int nf = 0; nf < 2; ++nf) {
          int d = nf * 16 + lr;
          float x1 = acc[mf][nf][r] + bias[colm + d];
          float x2 = acc[mf][nf + 2][r] + bias[colm + d + 32];
          float cth = ct[s * 32 + d], sth = st[s * 32 + d];
          oh[rowb + d]      = f2bf((x1 * cth - x2 * sth) * scale);
          oh[rowb + d + 32] = f2bf((x2 * cth + x1 * sth) * scale);
        }
      }
    }
  } else {
#pragma unroll
    for (int mf = 0; mf < 4; ++mf) {
      int mB = m0 + wr + mf * 16 + lg * 4;
      int b = mB >> 11, s0 = mB & (S_ - 1);
#pragma unroll
      for (int nf = 0; nf < 4; ++nf) {
        int d = nf * 16 + lr;
        float bi = bias[colm + d];
        ushort4 pk;
        pk.x = f2bf(acc[mf][nf][0] + bi);
        pk.y = f2bf(acc[mf][nf][1] + bi);
        pk.z = f2bf(acc[mf][nf][2] + bi);
        pk.w = f2bf(acc[mf][nf][3] + bi);
        *(ushort4*)&vt[(((size_t)b * NH_ + h) * HD_ + d) * S_ + s0] = pk;
      }
    }
  }
}

// ---------------- Flash attention: swapped QK^T, exp2 softmax, l-via-MFMA ----
// LDS: K [128 kv][64 d] @0 (16K), V^T [64 d][128 kv] @16K, mask*log2e @32K (8K).
__global__ __launch_bounds__(256, 2)
void attn_mfma_kernel(const u16* __restrict__ qw, const u16* __restrict__ kw,
                      const u16* __restrict__ vt, const float* __restrict__ mask,
                      float* __restrict__ outp) {
  __shared__ __align__(16) char smem[40960];
  constexpr int VTB = 16384, MS = 32768;
  const int tid = threadIdx.x;
  const int wave = tid >> 6, lane = tid & 63;
  const int lr = lane & 15, lg = lane >> 4;

  // XCD-chunked: 512 blocks, each XCD owns 4 heads x 16 q-tiles
  const int bid = blockIdx.x;
  const int idx = bid >> 3;
  const int bh = (bid & 7) * 4 + (idx >> 4);
  const int q0 = (idx & 15) * 128;
  const int b = bh >> 4, h = bh & 15;
  const size_t hb = (size_t)bh * S_ * HD_;

  // stage mask row scaled by log2(e) (8KB)
  {
    const float* mrow = mask + (size_t)b * S_ + tid * 8;
    float4 v0 = *(const float4*)mrow;
    float4 v1 = *(const float4*)(mrow + 4);
    v0.x *= LOG2E; v0.y *= LOG2E; v0.z *= LOG2E; v0.w *= LOG2E;
    v1.x *= LOG2E; v1.y *= LOG2E; v1.z *= LOG2E; v1.w *= LOG2E;
    *(float4*)(smem + MS + tid * 32) = v0;
    *(float4*)(smem + MS + tid * 32 + 16) = v1;
  }

  // Q fragments (B-operand): lane holds Q[q0 + wave*32 + qb*16 + lr][t*32 + lg*8 + j]
  bf16x8 aq[2][2];
#pragma unroll
  for (int qb = 0; qb < 2; ++qb) {
    size_t base = hb + (size_t)(q0 + wave * 32 + qb * 16 + lr) * HD_ + lg * 8;
    aq[qb][0] = *(const bf16x8*)&qw[base];
    aq[qb][1] = *(const bf16x8*)&qw[base + 32];
  }

  // ones A-fragment (row 0 = 1s) for l = sum(P) via MFMA
  bf16x8 ones_f;
  {
    unsigned int w = (lr == 0) ? 0x3F803F80u : 0u;
    u32x4 f = {w, w, w, w};
    ones_f = *(bf16x8*)&f;
  }

  f32x4 O[2][4], O4[2];
  float mrun[2];
#pragma unroll
  for (int qb = 0; qb < 2; ++qb) {
    mrun[qb] = -INFINITY;
    O4[qb] = (f32x4){0.f, 0.f, 0.f, 0.f};
#pragma unroll
    for (int dt = 0; dt < 4; ++dt) O[qb][dt] = (f32x4){0.f, 0.f, 0.f, 0.f};
  }

  // staging offsets (global source pre-swizzled, LDS dest linear)
  size_t kgo[4], vgo[4];
  int klo_[4], vlo_[4];
#pragma unroll
  for (int i = 0; i < 4; ++i) {
    int a = i * 4096 + tid * 16;
    {
      int row = a >> 7, seg = (a >> 4) & 7;
      kgo[i] = (size_t)row * HD_ + ((seg ^ (row & 7)) * 8);
      klo_[i] = a;
    }
    {
      int row = a >> 8, seg = (a >> 4) & 15;
      int sg = (seg & 8) | ((seg & 7) ^ (row & 7));
      vgo[i] = (size_t)row * S_ + sg * 8;
      vlo_[i] = VTB + a;
    }
  }

  const int sw = (lr & 7) << 4;

  for (int k0 = 0; k0 < S_; k0 += 128) {
    __syncthreads();
#pragma unroll
    for (int i = 0; i < 4; ++i) {
      gll16(kw + hb + kgo[i] + (size_t)k0 * HD_, smem + klo_[i]);
      gll16(vt + hb + vgo[i] + k0, smem + vlo_[i]);
    }
    __syncthreads();

    // S^T = K Q^T : lane gets S[q=lr][kv = c*16 + lg*4 + r]
    f32x4 sc[2][8];
#pragma unroll
    for (int qb = 0; qb < 2; ++qb)
#pragma unroll
      for (int c = 0; c < 8; ++c) sc[qb][c] = (f32x4){0.f, 0.f, 0.f, 0.f};
    __builtin_amdgcn_s_setprio(1);
#pragma unroll
    for (int t2 = 0; t2 < 2; ++t2) {
#pragma unroll
      for (int c = 0; c < 8; ++c) {
        int off = ((c * 16 + lr) << 7) + ((t2 * 64 + lg * 16) ^ sw);
        bf16x8 kf = *(const bf16x8*)(smem + off);
        sc[0][c] = __builtin_amdgcn_mfma_f32_16x16x32_bf16(kf, aq[0][t2], sc[0][c], 0, 0, 0);
        sc[1][c] = __builtin_amdgcn_mfma_f32_16x16x32_bf16(kf, aq[1][t2], sc[1][c], 0, 0, 0);
      }
    }
    __builtin_amdgcn_s_setprio(0);

    f32x4 mk[8];
#pragma unroll
    for (int c = 0; c < 8; ++c)
      mk[c] = *(const f32x4*)(smem + MS + (k0 + c * 16 + lg * 4) * 4);

    // softmax (exp2 domain) + in-register P-fragment build
    bf16x8 pf[2][4];
#pragma unroll
    for (int qb = 0; qb < 2; ++qb) {
      float mx = -INFINITY;
#pragma unroll
      for (int c = 0; c < 8; ++c) {
        sc[qb][c] += mk[c];
#pragma unroll
        for (int r = 0; r < 4; ++r) mx = fmaxf(mx, sc[qb][c][r]);
      }
      mx = fmaxf(mx, __shfl_xor(mx, 16));
      mx = fmaxf(mx, __shfl_xor(mx, 32));
      if (mx > mrun[qb] + 8.f) {          // defer-max: tolerate p up to 2^8
        float corr = __builtin_amdgcn_exp2f(mrun[qb] - mx);
        mrun[qb] = mx;
        O4[qb] *= corr;
#pragma unroll
        for (int dt = 0; dt < 4; ++dt) O[qb][dt] *= corr;
      }
#pragma unroll
      for (int c = 0; c < 8; ++c)
#pragma unroll
        for (int r = 0; r < 4; ++r)
          sc[qb][c][r] = __builtin_amdgcn_exp2f(sc[qb][c][r] - mrun[qb]);

      // pack P (bf16 pairs) then redistribute: lane lg gets kv = kt*32 + lg*8 + j
#pragma unroll
      for (int kt = 0; kt < 4; ++kt) {
        unsigned int x0 = cvtpk(sc[qb][2 * kt][0], sc[qb][2 * kt][1]);
        unsigned int x1 = cvtpk(sc[qb][2 * kt + 1][0], sc[qb][2 * kt + 1][1]);
        unsigned int y0 = cvtpk(sc[qb][2 * kt][2], sc[qb][2 * kt][3]);
        unsigned int y1 = cvtpk(sc[qb][2 * kt + 1][2], sc[qb][2 * kt + 1][3]);
        swap32(x0, x1);
        swap16(x0, x1);
        swap32(y0, y1);
        swap16(y0, y1);
        u32x4 f = {x0, y0, x1, y1};
        pf[qb][kt] = *(bf16x8*)&f;
      }
    }

    // O^T += V^T P^T ; l accumulated as row 0 of the ones-MFMA
    __builtin_amdgcn_s_setprio(1);
#pragma unroll
    for (int kt = 0; kt < 4; ++kt) {
      O4[0] = __builtin_amdgcn_mfma_f32_16x16x32_bf16(ones_f, pf[0][kt], O4[0], 0, 0, 0);
      O4[1] = __builtin_amdgcn_mfma_f32_16x16x32_bf16(ones_f, pf[1][kt], O4[1], 0, 0, 0);
#pragma unroll
      for (int dt = 0; dt < 4; ++dt) {
        int off = VTB + ((dt * 16 + lr) << 8) + ((kt * 64 + lg * 16) ^ sw);
        bf16x8 vf = *(const bf16x8*)(smem + off);
        O[0][dt] = __builtin_amdgcn_mfma_f32_16x16x32_bf16(vf, pf[0][kt], O[0][dt], 0, 0, 0);
        O[1][dt] = __builtin_amdgcn_mfma_f32_16x16x32_bf16(vf, pf[1][kt], O[1][dt], 0, 0, 0);
      }
    }
    __builtin_amdgcn_s_setprio(0);
  }

  // epilogue: l = O4 row0 (lives at lg==0, reg 0, col=q) -> broadcast via shfl
#pragma unroll
  for (int qb = 0; qb < 2; ++qb) {
    float l = __shfl(O4[qb][0], lr, 64);
    float inv = 1.0f / l;
    int s = q0 + wave * 32 + qb * 16 + lr;
    size_t rowb = ((size_t)b * S_ + s) * HID_ + h * HD_;
#pragma unroll
    for (int dt = 0; dt < 4; ++dt) {
      float4 r;
      r.x = O[qb][dt][0] * inv;
      r.y = O[qb][dt][1] * inv;
      r.z = O[qb][dt][2] * inv;
      r.w = O[qb][dt][3] * inv;
      *(float4*)&outp[rowb + dt * 16 + lg * 4] = r;
    }
  }
}

}  // namespace

extern "C" void kernel_launch(void* const* d_in, const int* in_sizes, int n_in,
                              void* d_out, int out_size, void* d_ws, size_t ws_size,
                              hipStream_t stream) {
  const float* hs   = (const float*)d_in[0];
  const float* mask = (const float*)d_in[1];
  const float* Wq   = (const float*)d_in[2];
  const float* bq   = (const float*)d_in[3];
  const float* Wk   = (const float*)d_in[4];
  const float* bk   = (const float*)d_in[5];
  const float* Wv   = (const float*)d_in[6];
  const float* bv   = (const float*)d_in[7];

  u16* qw = (u16*)d_ws;                  // [B,NH,S,HD] bf16 (rope + scale*log2e)
  u16* kw = qw + QSZ;                    // [B,NH,S,HD] bf16 (rope)
  u16* vt = kw + QSZ;                    // [B,NH,HD,S] bf16
  u16* hh = vt + QSZ;                    // [M, HID] bf16
  u16* wt = hh + (size_t)M_ * HID_;      // [3][1024][1024] transposed bf16
  float* ct = (float*)(wt + (size_t)3 * 1024 * 1024);
  float* st = ct + TBL;

  rope_table_kernel<<<TBL / 256, 256, 0, stream>>>(ct, st);
  convert_hs_kernel<<<(M_ * HID_) / 1024, 256, 0, stream>>>(hs, hh);
  transpose_w_kernel<<<dim3(16, 16, 3), 256, 0, stream>>>(Wq, Wk, Wv, wt);

  proj_gemm_kernel<<<768, 256, 0, stream>>>(hh, wt, bq, bk, bv, ct, st, qw, kw, vt);

  attn_mfma_kernel<<<512, 256, 0, stream>>>(qw, kw, vt, mask, (float*)d_out);
}

// Round 8
// 112.725 us; speedup vs baseline: 8.2542x; 1.0105x over previous
//
#include <hip/hip_runtime.h>
#include <math.h>

namespace {
constexpr int B_ = 2, S_ = 2048, HID_ = 1024, NH_ = 16, HD_ = 64;
constexpr int M_ = B_ * S_;                 // 4096 rows
constexpr int QSZ = B_ * NH_ * S_ * HD_;    // 4194304 elements per tensor
constexpr int TBL = S_ * (HD_ / 2);         // 65536 cos/sin entries
constexpr float LOG2E = 1.4426950408889634f;

typedef float f32x4 __attribute__((ext_vector_type(4)));
typedef __bf16 bf16x8 __attribute__((ext_vector_type(8)));
typedef unsigned int u32x4 __attribute__((ext_vector_type(4)));
typedef unsigned short u16;

__device__ inline u16 f2bf(float x) {
  unsigned int u = __float_as_uint(x);
  return (u16)((u + 0x7fffu + ((u >> 16) & 1u)) >> 16);
}
__device__ inline float bf2f(u16 h) {
  return __uint_as_float(((unsigned int)h) << 16);
}

typedef __attribute__((address_space(1))) const unsigned int as1_u32;
typedef __attribute__((address_space(3))) unsigned int as3_u32;
__device__ __forceinline__ void gll16(const void* g, void* l) {
  __builtin_amdgcn_global_load_lds((as1_u32*)g, (as3_u32*)l, 16, 0, 0);
}

// gfx950 cross-lane row swaps (VALU, no LDS pipe)
__device__ __forceinline__ void swap32(unsigned int& a, unsigned int& b) {
  asm("v_permlane32_swap_b32 %0, %1" : "+v"(a), "+v"(b));
}
__device__ __forceinline__ void swap16(unsigned int& a, unsigned int& b) {
  asm("v_permlane16_swap_b32 %0, %1" : "+v"(a), "+v"(b));
}
__device__ __forceinline__ unsigned int cvtpk(float lo, float hi) {
  unsigned int r;
  asm("v_cvt_pk_bf16_f32 %0, %1, %2" : "=v"(r) : "v"(lo), "v"(hi));
  return r;
}

// ---------------- RoPE cos/sin table ----------------
__global__ void rope_table_kernel(float* __restrict__ ct, float* __restrict__ st) {
  int t = blockIdx.x * blockDim.x + threadIdx.x;
  if (t >= TBL) return;
  int s = t >> 5, i = t & 31;
  float inv = 1.0f / powf(10000.0f, (float)(2 * i) / (float)HD_);
  float ang = (float)s * inv;
  double a = (double)ang;
  ct[t] = (float)cos(a);
  st[t] = (float)sin(a);
}

// ---------------- hs -> bf16 ----------------
__global__ __launch_bounds__(256)
void convert_hs_kernel(const float* __restrict__ hs, u16* __restrict__ hh) {
  size_t t = (size_t)blockIdx.x * 256 + threadIdx.x;
  float4 v = *(const float4*)&hs[t * 4];
  short4 hi = {(short)f2bf(v.x), (short)f2bf(v.y), (short)f2bf(v.z), (short)f2bf(v.w)};
  *(short4*)&hh[t * 4] = hi;
}

// ---------------- W -> W^T bf16  (wt[3][n][k]) ----------------
__global__ __launch_bounds__(256)
void transpose_w_kernel(const float* __restrict__ Wq, const float* __restrict__ Wk,
                        const float* __restrict__ Wv, u16* __restrict__ wt) {
  __shared__ float tile[64][65];
  const float* W = blockIdx.z == 0 ? Wq : blockIdx.z == 1 ? Wk : Wv;
  int k0 = blockIdx.x * 64, n0 = blockIdx.y * 64;
  int t = threadIdx.x;
  int lrow = t >> 4, lcol = (t & 15) * 4;
#pragma unroll
  for (int i = 0; i < 4; ++i) {
    float4 v = *(const float4*)&W[(size_t)(k0 + lrow + i * 16) * HID_ + n0 + lcol];
    tile[lrow + i * 16][lcol + 0] = v.x;
    tile[lrow + i * 16][lcol + 1] = v.y;
    tile[lrow + i * 16][lcol + 2] = v.z;
    tile[lrow + i * 16][lcol + 3] = v.w;
  }
  __syncthreads();
  int n = t >> 2, ks = (t & 3) * 16;
  u16 tmp[16];
#pragma unroll
  for (int j = 0; j < 16; ++j) tmp[j] = f2bf(tile[ks + j][n]);
  u16* dst = &wt[((size_t)blockIdx.z * 1024 + n0 + n) * 1024 + k0 + ks];
  ((uint4*)dst)[0] = ((uint4*)tmp)[0];
  ((uint4*)dst)[1] = ((uint4*)tmp)[1];
}

// ---------------- Fused QKV projection on MFMA (dbuf, counted vmcnt) ----------
__global__ __launch_bounds__(256)
void proj_gemm_kernel(const u16* __restrict__ Ah, const u16* __restrict__ Wt,
                      const float* __restrict__ bq, const float* __restrict__ bk,
                      const float* __restrict__ bv,
                      const float* __restrict__ ct, const float* __restrict__ st,
                      u16* __restrict__ qw, u16* __restrict__ kw, u16* __restrict__ vt) {
  __shared__ u16 sAh[2][128 * 64];
  __shared__ u16 sB[2][128 * 64];
  const int tid = threadIdx.x;
  const int wave = tid >> 6, lane = tid & 63;
  const int lr = lane & 15, lg = lane >> 4;

  int bid = blockIdx.x;
  int swz = (bid & 7) * 96 + (bid >> 3);
  const int gx = swz / 24, gy = swz % 24;
  const int m0 = gx * 128;
  const int ng0 = gy * 128;

  size_t aoff[4], boff[4];
  int c16[4];
#pragma unroll
  for (int i = 0; i < 4; ++i) {
    int c = i * 256 + tid;
    int row = c >> 3, ks = c & 7;
    int kph = (ks ^ (row & 7)) * 8;
    aoff[i] = (size_t)(m0 + row) * HID_ + kph;
    boff[i] = (size_t)(ng0 + row) * HID_ + kph;
    c16[i] = c * 16;
  }

  const int wr = (wave >> 1) * 64, wc = (wave & 1) * 64;
  int offA[4][2], offB[4][2];
#pragma unroll
  for (int f = 0; f < 4; ++f) {
    int ra = wr + f * 16 + lr;
    int rb = wc + f * 16 + lr;
#pragma unroll
    for (int kk = 0; kk < 2; ++kk) {
      offA[f][kk] = ra * 128 + (((kk * 4 + lg)) ^ (ra & 7)) * 16;
      offB[f][kk] = rb * 128 + (((kk * 4 + lg)) ^ (rb & 7)) * 16;
    }
  }

  f32x4 acc[4][4];
#pragma unroll
  for (int mf = 0; mf < 4; ++mf)
#pragma unroll
    for (int nf = 0; nf < 4; ++nf) acc[mf][nf] = (f32x4){0.f, 0.f, 0.f, 0.f};

  // prologue: stage K-step 0 into buffer 0
#pragma unroll
  for (int i = 0; i < 4; ++i) {
    gll16(Ah + aoff[i], (char*)sAh[0] + c16[i]);
    gll16(Wt + boff[i], (char*)sB[0] + c16[i]);
  }
  __syncthreads();

  for (int t = 0; t < 16; ++t) {
    if (t < 15) {
      const int nb = (t + 1) & 1;
      const int k0n = (t + 1) * 64;
#pragma unroll
      for (int i = 0; i < 4; ++i) {
        gll16(Ah + aoff[i] + k0n, (char*)sAh[nb] + c16[i]);
        gll16(Wt + boff[i] + k0n, (char*)sB[nb] + c16[i]);
      }
      asm volatile("s_waitcnt vmcnt(8)" ::: "memory");
    } else {
      asm volatile("s_waitcnt vmcnt(0)" ::: "memory");
    }
    __builtin_amdgcn_s_barrier();
    __builtin_amdgcn_sched_barrier(0);

    const char* sa = (const char*)sAh[t & 1];
    const char* sb = (const char*)sB[t & 1];
#pragma unroll
    for (int kk = 0; kk < 2; ++kk) {
      bf16x8 a_h[4], bb[4];
#pragma unroll
      for (int f = 0; f < 4; ++f) {
        a_h[f] = *(const bf16x8*)(sa + offA[f][kk]);
        bb[f] = *(const bf16x8*)(sb + offB[f][kk]);
      }
      __builtin_amdgcn_s_setprio(1);
#pragma unroll
      for (int mf = 0; mf < 4; ++mf)
#pragma unroll
        for (int nf = 0; nf < 4; ++nf)
          acc[mf][nf] = __builtin_amdgcn_mfma_f32_16x16x32_bf16(a_h[mf], bb[nf], acc[mf][nf], 0, 0, 0);
      __builtin_amdgcn_s_setprio(0);
    }
    __builtin_amdgcn_sched_barrier(0);
    __builtin_amdgcn_s_barrier();
  }

  const int which = gy >> 3;
  const int colm = (gy & 7) * 128 + wc;
  const int h = colm >> 6;
  const float* bias = which == 0 ? bq : which == 1 ? bk : bv;
  // Q folds HD^-0.5 AND log2(e) for the exp2-domain softmax
  const float scale = which == 0 ? 0.125f * LOG2E : 1.0f;

  if (which < 2) {
    u16* oh = which == 0 ? qw : kw;
#pragma unroll
    for (int mf = 0; mf < 4; ++mf) {
#pragma unroll
      for (int r = 0; r < 4; ++r) {
        int m = m0 + wr + mf * 16 + lg * 4 + r;
        int b = m >> 11, s = m & (S_ - 1);
        size_t rowb = (((size_t)b * NH_ + h) * S_ + s) * HD_;
#pragma unroll
        for (int nf = 0; nf < 2; ++nf) {
          int d = nf * 16 + lr;
          float x1 = acc[mf][nf][r] + bias[colm + d];
          float x2 = acc[mf][nf + 2][r] + bias[colm + d + 32];
          float cth = ct[s * 32 + d], sth = st[s * 32 + d];
          oh[rowb + d]      = f2bf((x1 * cth - x2 * sth) * scale);
          oh[rowb + d + 32] = f2bf((x2 * cth + x1 * sth) * scale);
        }
      }
    }
  } else {
#pragma unroll
    for (int mf = 0; mf < 4; ++mf) {
      int mB = m0 + wr + mf * 16 + lg * 4;
      int b = mB >> 11, s0 = mB & (S_ - 1);
#pragma unroll
      for (int nf = 0; nf < 4; ++nf) {
        int d = nf * 16 + lr;
        float bi = bias[colm + d];
        ushort4 pk;
        pk.x = f2bf(acc[mf][nf][0] + bi);
        pk.y = f2bf(acc[mf][nf][1] + bi);
        pk.z = f2bf(acc[mf][nf][2] + bi);
        pk.w = f2bf(acc[mf][nf][3] + bi);
        *(ushort4*)&vt[(((size_t)b * NH_ + h) * HD_ + d) * S_ + s0] = pk;
      }
    }
  }
}

// ---------------- Flash attention: dbuf KVBLK=64, counted vmcnt ----
// LDS: buf0 {K 8K | V^T 8K} @0, buf1 @16K, mask*log2e @32K (8K). Total 40K.
__global__ __launch_bounds__(256, 2)
void attn_mfma_kernel(const u16* __restrict__ qw, const u16* __restrict__ kw,
                      const u16* __restrict__ vt, const float* __restrict__ mask,
                      float* __restrict__ outp) {
  __shared__ __align__(16) char smem[40960];
  constexpr int MS = 32768;
  const int tid = threadIdx.x;
  const int wave = tid >> 6, lane = tid & 63;
  const int lr = lane & 15, lg = lane >> 4;

  // XCD-chunked: 512 blocks, each XCD owns 4 heads x 16 q-tiles
  const int bid = blockIdx.x;
  const int idx = bid >> 3;
  const int bh = (bid & 7) * 4 + (idx >> 4);
  const int q0 = (idx & 15) * 128;
  const int b = bh >> 4, h = bh & 15;
  const size_t hb = (size_t)bh * S_ * HD_;

  // stage mask row scaled by log2(e) (8KB)
  {
    const float* mrow = mask + (size_t)b * S_ + tid * 8;
    float4 v0 = *(const float4*)mrow;
    float4 v1 = *(const float4*)(mrow + 4);
    v0.x *= LOG2E; v0.y *= LOG2E; v0.z *= LOG2E; v0.w *= LOG2E;
    v1.x *= LOG2E; v1.y *= LOG2E; v1.z *= LOG2E; v1.w *= LOG2E;
    *(float4*)(smem + MS + tid * 32) = v0;
    *(float4*)(smem + MS + tid * 32 + 16) = v1;
  }

  // Q fragments (B-operand): lane holds Q[q0 + wave*32 + qb*16 + lr][t*32 + lg*8 + j]
  bf16x8 aq[2][2];
#pragma unroll
  for (int qb = 0; qb < 2; ++qb) {
    size_t base = hb + (size_t)(q0 + wave * 32 + qb * 16 + lr) * HD_ + lg * 8;
    aq[qb][0] = *(const bf16x8*)&qw[base];
    aq[qb][1] = *(const bf16x8*)&qw[base + 32];
  }

  // ones A-fragment (row 0 = 1s) for l = sum(P) via MFMA
  bf16x8 ones_f;
  {
    unsigned int w = (lr == 0) ? 0x3F803F80u : 0u;
    u32x4 f = {w, w, w, w};
    ones_f = *(bf16x8*)&f;
  }

  f32x4 O[2][4], O4[2];
  float mrun[2];
#pragma unroll
  for (int qb = 0; qb < 2; ++qb) {
    mrun[qb] = -INFINITY;
    O4[qb] = (f32x4){0.f, 0.f, 0.f, 0.f};
#pragma unroll
    for (int dt = 0; dt < 4; ++dt) O[qb][dt] = (f32x4){0.f, 0.f, 0.f, 0.f};
  }

  // staging offsets: K and V tiles are both 64 rows x 128 B (4096 B per issue)
  size_t kgo[2], vgo[2];
  int klo_[2], vlo_[2];
#pragma unroll
  for (int i = 0; i < 2; ++i) {
    int a = i * 4096 + tid * 16;
    int row = a >> 7, seg = (a >> 4) & 7;
    int sseg = (seg ^ (row & 7)) * 8;
    kgo[i] = (size_t)row * HD_ + sseg;
    klo_[i] = a;
    vgo[i] = (size_t)row * S_ + sseg;
    vlo_[i] = 8192 + a;
  }

  const int sw = (lr & 7) << 4;

#define STAGE_KV(T, BASE)                                                   \
  {                                                                         \
    _Pragma("unroll") for (int i = 0; i < 2; ++i) {                         \
      gll16(kw + hb + kgo[i] + (size_t)(T) * 64 * HD_, smem + (BASE) + klo_[i]); \
      gll16(vt + hb + vgo[i] + (T) * 64, smem + (BASE) + vlo_[i]);          \
    }                                                                       \
  }

  STAGE_KV(0, 0);
  __syncthreads();  // drains prologue staging + mask stores

  for (int t = 0; t < 32; ++t) {
    const int base = (t & 1) << 14;
    if (t < 31) {
      STAGE_KV(t + 1, ((t + 1) & 1) << 14);
      asm volatile("s_waitcnt vmcnt(4)" ::: "memory");
    } else {
      asm volatile("s_waitcnt vmcnt(0)" ::: "memory");
    }
    __builtin_amdgcn_s_barrier();
    __builtin_amdgcn_sched_barrier(0);

    // S^T = K Q^T : lane gets S[q=lr][kv = c*16 + lg*4 + r]
    f32x4 sc[2][4];
#pragma unroll
    for (int qb = 0; qb < 2; ++qb)
#pragma unroll
      for (int c = 0; c < 4; ++c) sc[qb][c] = (f32x4){0.f, 0.f, 0.f, 0.f};
    __builtin_amdgcn_s_setprio(1);
#pragma unroll
    for (int t2 = 0; t2 < 2; ++t2) {
#pragma unroll
      for (int c = 0; c < 4; ++c) {
        int off = base + ((c * 16 + lr) << 7) + ((t2 * 64 + lg * 16) ^ sw);
        bf16x8 kf = *(const bf16x8*)(smem + off);
        sc[0][c] = __builtin_amdgcn_mfma_f32_16x16x32_bf16(kf, aq[0][t2], sc[0][c], 0, 0, 0);
        sc[1][c] = __builtin_amdgcn_mfma_f32_16x16x32_bf16(kf, aq[1][t2], sc[1][c], 0, 0, 0);
      }
    }
    __builtin_amdgcn_s_setprio(0);

    f32x4 mk[4];
#pragma unroll
    for (int c = 0; c < 4; ++c)
      mk[c] = *(const f32x4*)(smem + MS + (t * 64 + c * 16 + lg * 4) * 4);

    // softmax (exp2 domain) + in-register P-fragment build
    bf16x8 pf[2][2];
#pragma unroll
    for (int qb = 0; qb < 2; ++qb) {
      float mx = -INFINITY;
#pragma unroll
      for (int c = 0; c < 4; ++c) {
        sc[qb][c] += mk[c];
#pragma unroll
        for (int r = 0; r < 4; ++r) mx = fmaxf(mx, sc[qb][c][r]);
      }
      mx = fmaxf(mx, __shfl_xor(mx, 16));
      mx = fmaxf(mx, __shfl_xor(mx, 32));
      if (mx > mrun[qb] + 8.f) {          // defer-max: tolerate p up to 2^8
        float corr = __builtin_amdgcn_exp2f(mrun[qb] - mx);
        mrun[qb] = mx;
        O4[qb] *= corr;
#pragma unroll
        for (int dt = 0; dt < 4; ++dt) O[qb][dt] *= corr;
      }
#pragma unroll
      for (int c = 0; c < 4; ++c)
#pragma unroll
        for (int r = 0; r < 4; ++r)
          sc[qb][c][r] = __builtin_amdgcn_exp2f(sc[qb][c][r] - mrun[qb]);

      // pack P (bf16 pairs) then redistribute: lane lg gets kv = kt*32 + lg*8 + j
#pragma unroll
      for (int kt = 0; kt < 2; ++kt) {
        unsigned int x0 = cvtpk(sc[qb][2 * kt][0], sc[qb][2 * kt][1]);
        unsigned int x1 = cvtpk(sc[qb][2 * kt + 1][0], sc[qb][2 * kt + 1][1]);
        unsigned int y0 = cvtpk(sc[qb][2 * kt][2], sc[qb][2 * kt][3]);
        unsigned int y1 = cvtpk(sc[qb][2 * kt + 1][2], sc[qb][2 * kt + 1][3]);
        swap32(x0, x1);
        swap16(x0, x1);
        swap32(y0, y1);
        swap16(y0, y1);
        u32x4 f = {x0, y0, x1, y1};
        pf[qb][kt] = *(bf16x8*)&f;
      }
    }

    // O^T += V^T P^T ; l accumulated as row 0 of the ones-MFMA
    __builtin_amdgcn_s_setprio(1);
#pragma unroll
    for (int kt = 0; kt < 2; ++kt) {
      O4[0] = __builtin_amdgcn_mfma_f32_16x16x32_bf16(ones_f, pf[0][kt], O4[0], 0, 0, 0);
      O4[1] = __builtin_amdgcn_mfma_f32_16x16x32_bf16(ones_f, pf[1][kt], O4[1], 0, 0, 0);
#pragma unroll
      for (int dt = 0; dt < 4; ++dt) {
        int off = base + 8192 + ((dt * 16 + lr) << 7) + ((kt * 64 + lg * 16) ^ sw);
        bf16x8 vf = *(const bf16x8*)(smem + off);
        O[0][dt] = __builtin_amdgcn_mfma_f32_16x16x32_bf16(vf, pf[0][kt], O[0][dt], 0, 0, 0);
        O[1][dt] = __builtin_amdgcn_mfma_f32_16x16x32_bf16(vf, pf[1][kt], O[1][dt], 0, 0, 0);
      }
    }
    __builtin_amdgcn_s_setprio(0);

    __builtin_amdgcn_sched_barrier(0);
    __builtin_amdgcn_s_barrier();
  }

  // epilogue: l = O4 row0 (lives at lg==0, reg 0, col=q) -> broadcast via shfl
#pragma unroll
  for (int qb = 0; qb < 2; ++qb) {
    float l = __shfl(O4[qb][0], lr, 64);
    float inv = 1.0f / l;
    int s = q0 + wave * 32 + qb * 16 + lr;
    size_t rowb = ((size_t)b * S_ + s) * HID_ + h * HD_;
#pragma unroll
    for (int dt = 0; dt < 4; ++dt) {
      float4 r;
      r.x = O[qb][dt][0] * inv;
      r.y = O[qb][dt][1] * inv;
      r.z = O[qb][dt][2] * inv;
      r.w = O[qb][dt][3] * inv;
      *(float4*)&outp[rowb + dt * 16 + lg * 4] = r;
    }
  }
#undef STAGE_KV
}

}  // namespace

extern "C" void kernel_launch(void* const* d_in, const int* in_sizes, int n_in,
                              void* d_out, int out_size, void* d_ws, size_t ws_size,
                              hipStream_t stream) {
  const float* hs   = (const float*)d_in[0];
  const float* mask = (const float*)d_in[1];
  const float* Wq   = (const float*)d_in[2];
  const float* bq   = (const float*)d_in[3];
  const float* Wk   = (const float*)d_in[4];
  const float* bk   = (const float*)d_in[5];
  const float* Wv   = (const float*)d_in[6];
  const float* bv   = (const float*)d_in[7];

  u16* qw = (u16*)d_ws;                  // [B,NH,S,HD] bf16 (rope + scale*log2e)
  u16* kw = qw + QSZ;                    // [B,NH,S,HD] bf16 (rope)
  u16* vt = kw + QSZ;                    // [B,NH,HD,S] bf16
  u16* hh = vt + QSZ;                    // [M, HID] bf16
  u16* wt = hh + (size_t)M_ * HID_;      // [3][1024][1024] transposed bf16
  float* ct = (float*)(wt + (size_t)3 * 1024 * 1024);
  float* st = ct + TBL;

  rope_table_kernel<<<TBL / 256, 256, 0, stream>>>(ct, st);
  convert_hs_kernel<<<(M_ * HID_) / 1024, 256, 0, stream>>>(hs, hh);
  transpose_w_kernel<<<dim3(16, 16, 3), 256, 0, stream>>>(Wq, Wk, Wv, wt);

  proj_gemm_kernel<<<768, 256, 0, stream>>>(hh, wt, bq, bk, bv, ct, st, qw, kw, vt);

  attn_mfma_kernel<<<512, 256, 0, stream>>>(qw, kw, vt, mask, (float*)d_out);
}

// Round 10
// 106.768 us; speedup vs baseline: 8.7148x; 1.0558x over previous
//
#include <hip/hip_runtime.h>
#include <math.h>

namespace {
constexpr int B_ = 2, S_ = 2048, HID_ = 1024, NH_ = 16, HD_ = 64;
constexpr int M_ = B_ * S_;                 // 4096 rows
constexpr int QSZ = B_ * NH_ * S_ * HD_;    // 4194304 elements per tensor
constexpr int TBL = S_ * (HD_ / 2);         // 65536 cos/sin entries
constexpr float LOG2E = 1.4426950408889634f;

typedef float f32x4 __attribute__((ext_vector_type(4)));
typedef __bf16 bf16x8 __attribute__((ext_vector_type(8)));
typedef unsigned int u32x4 __attribute__((ext_vector_type(4)));
typedef unsigned short u16;

__device__ inline u16 f2bf(float x) {
  unsigned int u = __float_as_uint(x);
  return (u16)((u + 0x7fffu + ((u >> 16) & 1u)) >> 16);
}
__device__ inline float bf2f(u16 h) {
  return __uint_as_float(((unsigned int)h) << 16);
}

typedef __attribute__((address_space(1))) const unsigned int as1_u32;
typedef __attribute__((address_space(3))) unsigned int as3_u32;
__device__ __forceinline__ void gll16(const void* g, void* l) {
  __builtin_amdgcn_global_load_lds((as1_u32*)g, (as3_u32*)l, 16, 0, 0);
}

// gfx950 cross-lane row swaps (VALU, no LDS pipe)
__device__ __forceinline__ void swap32(unsigned int& a, unsigned int& b) {
  asm("v_permlane32_swap_b32 %0, %1" : "+v"(a), "+v"(b));
}
__device__ __forceinline__ void swap16(unsigned int& a, unsigned int& b) {
  asm("v_permlane16_swap_b32 %0, %1" : "+v"(a), "+v"(b));
}
__device__ __forceinline__ unsigned int cvtpk(float lo, float hi) {
  unsigned int r;
  asm("v_cvt_pk_bf16_f32 %0, %1, %2" : "=v"(r) : "v"(lo), "v"(hi));
  return r;
}

// ---------------- fused prep: hs->bf16 | W->W^T bf16 | rope table ----------------
// flat grid: [0,4096) convert_hs, [4096,4864) transpose_w, [4864,5120) rope table
__global__ __launch_bounds__(256)
void prep_kernel(const float* __restrict__ hs, u16* __restrict__ hh,
                 const float* __restrict__ Wq, const float* __restrict__ Wk,
                 const float* __restrict__ Wv, u16* __restrict__ wt,
                 float* __restrict__ ct, float* __restrict__ st) {
  __shared__ float tile[64][65];
  const int bid = blockIdx.x;
  const int t = threadIdx.x;
  if (bid < 4096) {
    size_t e = (size_t)bid * 256 + t;
    float4 v = *(const float4*)&hs[e * 4];
    short4 hi = {(short)f2bf(v.x), (short)f2bf(v.y), (short)f2bf(v.z), (short)f2bf(v.w)};
    *(short4*)&hh[e * 4] = hi;
  } else if (bid < 4864) {
    int r = bid - 4096;
    int bx = r & 15, by = (r >> 4) & 15, bz = r >> 8;
    const float* W = bz == 0 ? Wq : bz == 1 ? Wk : Wv;
    int k0 = bx * 64, n0 = by * 64;
    int lrow = t >> 4, lcol = (t & 15) * 4;
#pragma unroll
    for (int i = 0; i < 4; ++i) {
      float4 v = *(const float4*)&W[(size_t)(k0 + lrow + i * 16) * HID_ + n0 + lcol];
      tile[lrow + i * 16][lcol + 0] = v.x;
      tile[lrow + i * 16][lcol + 1] = v.y;
      tile[lrow + i * 16][lcol + 2] = v.z;
      tile[lrow + i * 16][lcol + 3] = v.w;
    }
    __syncthreads();
    int n = t >> 2, ks = (t & 3) * 16;
    u16 tmp[16];
#pragma unroll
    for (int j = 0; j < 16; ++j) tmp[j] = f2bf(tile[ks + j][n]);
    u16* dst = &wt[((size_t)bz * 1024 + n0 + n) * 1024 + k0 + ks];
    ((uint4*)dst)[0] = ((uint4*)tmp)[0];
    ((uint4*)dst)[1] = ((uint4*)tmp)[1];
  } else {
    int e = (bid - 4864) * 256 + t;
    int s = e >> 5, i = e & 31;
    float inv = 1.0f / powf(10000.0f, (float)(2 * i) / (float)HD_);
    float ang = (float)s * inv;
    double a = (double)ang;
    ct[e] = (float)cos(a);
    st[e] = (float)sin(a);
  }
}

// ---------------- Fused QKV projection on MFMA (dbuf, counted vmcnt) ----------
__global__ __launch_bounds__(256)
void proj_gemm_kernel(const u16* __restrict__ Ah, const u16* __restrict__ Wt,
                      const float* __restrict__ bq, const float* __restrict__ bk,
                      const float* __restrict__ bv,
                      const float* __restrict__ ct, const float* __restrict__ st,
                      u16* __restrict__ qw, u16* __restrict__ kw, u16* __restrict__ vt) {
  __shared__ u16 sAh[2][128 * 64];
  __shared__ u16 sB[2][128 * 64];
  const int tid = threadIdx.x;
  const int wave = tid >> 6, lane = tid & 63;
  const int lr = lane & 15, lg = lane >> 4;

  int bid = blockIdx.x;
  int swz = (bid & 7) * 96 + (bid >> 3);
  const int gx = swz / 24, gy = swz % 24;
  const int m0 = gx * 128;
  const int ng0 = gy * 128;

  size_t aoff[4], boff[4];
  int c16[4];
#pragma unroll
  for (int i = 0; i < 4; ++i) {
    int c = i * 256 + tid;
    int row = c >> 3, ks = c & 7;
    int kph = (ks ^ (row & 7)) * 8;
    aoff[i] = (size_t)(m0 + row) * HID_ + kph;
    boff[i] = (size_t)(ng0 + row) * HID_ + kph;
    c16[i] = c * 16;
  }

  const int wr = (wave >> 1) * 64, wc = (wave & 1) * 64;
  int offA[4][2], offB[4][2];
#pragma unroll
  for (int f = 0; f < 4; ++f) {
    int ra = wr + f * 16 + lr;
    int rb = wc + f * 16 + lr;
#pragma unroll
    for (int kk = 0; kk < 2; ++kk) {
      offA[f][kk] = ra * 128 + (((kk * 4 + lg)) ^ (ra & 7)) * 16;
      offB[f][kk] = rb * 128 + (((kk * 4 + lg)) ^ (rb & 7)) * 16;
    }
  }

  f32x4 acc[4][4];
#pragma unroll
  for (int mf = 0; mf < 4; ++mf)
#pragma unroll
    for (int nf = 0; nf < 4; ++nf) acc[mf][nf] = (f32x4){0.f, 0.f, 0.f, 0.f};

  // prologue: stage K-step 0 into buffer 0
#pragma unroll
  for (int i = 0; i < 4; ++i) {
    gll16(Ah + aoff[i], (char*)sAh[0] + c16[i]);
    gll16(Wt + boff[i], (char*)sB[0] + c16[i]);
  }
  __syncthreads();

  for (int t = 0; t < 16; ++t) {
    if (t < 15) {
      const int nb = (t + 1) & 1;
      const int k0n = (t + 1) * 64;
#pragma unroll
      for (int i = 0; i < 4; ++i) {
        gll16(Ah + aoff[i] + k0n, (char*)sAh[nb] + c16[i]);
        gll16(Wt + boff[i] + k0n, (char*)sB[nb] + c16[i]);
      }
      asm volatile("s_waitcnt vmcnt(8)" ::: "memory");
    } else {
      asm volatile("s_waitcnt vmcnt(0)" ::: "memory");
    }
    __builtin_amdgcn_s_barrier();
    __builtin_amdgcn_sched_barrier(0);

    const char* sa = (const char*)sAh[t & 1];
    const char* sb = (const char*)sB[t & 1];
#pragma unroll
    for (int kk = 0; kk < 2; ++kk) {
      bf16x8 a_h[4], bb[4];
#pragma unroll
      for (int f = 0; f < 4; ++f) {
        a_h[f] = *(const bf16x8*)(sa + offA[f][kk]);
        bb[f] = *(const bf16x8*)(sb + offB[f][kk]);
      }
      __builtin_amdgcn_s_setprio(1);
#pragma unroll
      for (int mf = 0; mf < 4; ++mf)
#pragma unroll
        for (int nf = 0; nf < 4; ++nf)
          acc[mf][nf] = __builtin_amdgcn_mfma_f32_16x16x32_bf16(a_h[mf], bb[nf], acc[mf][nf], 0, 0, 0);
      __builtin_amdgcn_s_setprio(0);
    }
    __builtin_amdgcn_sched_barrier(0);
    __builtin_amdgcn_s_barrier();
  }

  const int which = gy >> 3;
  const int colm = (gy & 7) * 128 + wc;
  const int h = colm >> 6;
  const float* bias = which == 0 ? bq : which == 1 ? bk : bv;
  // Q folds HD^-0.5 AND log2(e) for the exp2-domain softmax
  const float scale = which == 0 ? 0.125f * LOG2E : 1.0f;

  if (which < 2) {
    u16* oh = which == 0 ? qw : kw;
#pragma unroll
    for (int mf = 0; mf < 4; ++mf) {
#pragma unroll
      for (int r = 0; r < 4; ++r) {
        int m = m0 + wr + mf * 16 + lg * 4 + r;
        int b = m >> 11, s = m & (S_ - 1);
        size_t rowb = (((size_t)b * NH_ + h) * S_ + s) * HD_;
#pragma unroll
        for (int nf = 0; nf < 2; ++nf) {
          int d = nf * 16 + lr;
          float x1 = acc[mf][nf][r] + bias[colm + d];
          float x2 = acc[mf][nf + 2][r] + bias[colm + d + 32];
          float cth = ct[s * 32 + d], sth = st[s * 32 + d];
          oh[rowb + d]      = f2bf((x1 * cth - x2 * sth) * scale);
          oh[rowb + d + 32] = f2bf((x2 * cth + x1 * sth) * scale);
        }
      }
    }
  } else {
#pragma unroll
    for (int mf = 0; mf < 4; ++mf) {
      int mB = m0 + wr + mf * 16 + lg * 4;
      int b = mB >> 11, s0 = mB & (S_ - 1);
#pragma unroll
      for (int nf = 0; nf < 4; ++nf) {
        int d = nf * 16 + lr;
        float bi = bias[colm + d];
        ushort4 pk;
        pk.x = f2bf(acc[mf][nf][0] + bi);
        pk.y = f2bf(acc[mf][nf][1] + bi);
        pk.z = f2bf(acc[mf][nf][2] + bi);
        pk.w = f2bf(acc[mf][nf][3] + bi);
        *(ushort4*)&vt[(((size_t)b * NH_ + h) * HD_ + d) * S_ + s0] = pk;
      }
    }
  }
}

// ---------------- Flash attention: dbuf KVBLK=64, counted vmcnt (R8-exact) ----
// LDS: buf0 {K 8K | V^T 8K} @0, buf1 @16K, mask*log2e @32K (8K). Total 40K.
__global__ __launch_bounds__(256, 2)
void attn_mfma_kernel(const u16* __restrict__ qw, const u16* __restrict__ kw,
                      const u16* __restrict__ vt, const float* __restrict__ mask,
                      float* __restrict__ outp) {
  __shared__ __align__(16) char smem[40960];
  constexpr int MS = 32768;
  const int tid = threadIdx.x;
  const int wave = tid >> 6, lane = tid & 63;
  const int lr = lane & 15, lg = lane >> 4;

  // XCD-chunked: 512 blocks, each XCD owns 4 heads x 16 q-tiles
  const int bid = blockIdx.x;
  const int idx = bid >> 3;
  const int bh = (bid & 7) * 4 + (idx >> 4);
  const int q0 = (idx & 15) * 128;
  const int b = bh >> 4, h = bh & 15;
  const size_t hb = (size_t)bh * S_ * HD_;

  // stage mask row scaled by log2(e) (8KB)
  {
    const float* mrow = mask + (size_t)b * S_ + tid * 8;
    float4 v0 = *(const float4*)mrow;
    float4 v1 = *(const float4*)(mrow + 4);
    v0.x *= LOG2E; v0.y *= LOG2E; v0.z *= LOG2E; v0.w *= LOG2E;
    v1.x *= LOG2E; v1.y *= LOG2E; v1.z *= LOG2E; v1.w *= LOG2E;
    *(float4*)(smem + MS + tid * 32) = v0;
    *(float4*)(smem + MS + tid * 32 + 16) = v1;
  }

  // Q fragments (B-operand): lane holds Q[q0 + wave*32 + qb*16 + lr][t*32 + lg*8 + j]
  bf16x8 aq[2][2];
#pragma unroll
  for (int qb = 0; qb < 2; ++qb) {
    size_t base = hb + (size_t)(q0 + wave * 32 + qb * 16 + lr) * HD_ + lg * 8;
    aq[qb][0] = *(const bf16x8*)&qw[base];
    aq[qb][1] = *(const bf16x8*)&qw[base + 32];
  }

  // ones A-fragment (row 0 = 1s) for l = sum(P) via MFMA
  bf16x8 ones_f;
  {
    unsigned int w = (lr == 0) ? 0x3F803F80u : 0u;
    u32x4 f = {w, w, w, w};
    ones_f = *(bf16x8*)&f;
  }

  f32x4 O[2][4], O4[2];
  float mrun[2];
#pragma unroll
  for (int qb = 0; qb < 2; ++qb) {
    mrun[qb] = -INFINITY;
    O4[qb] = (f32x4){0.f, 0.f, 0.f, 0.f};
#pragma unroll
    for (int dt = 0; dt < 4; ++dt) O[qb][dt] = (f32x4){0.f, 0.f, 0.f, 0.f};
  }

  // staging offsets: K and V tiles are both 64 rows x 128 B (4096 B per issue)
  size_t kgo[2], vgo[2];
  int klo_[2], vlo_[2];
#pragma unroll
  for (int i = 0; i < 2; ++i) {
    int a = i * 4096 + tid * 16;
    int row = a >> 7, seg = (a >> 4) & 7;
    int sseg = (seg ^ (row & 7)) * 8;
    kgo[i] = (size_t)row * HD_ + sseg;
    klo_[i] = a;
    vgo[i] = (size_t)row * S_ + sseg;
    vlo_[i] = 8192 + a;
  }

  const int sw = (lr & 7) << 4;

#define STAGE_KV(T, BASE)                                                   \
  {                                                                         \
    _Pragma("unroll") for (int i = 0; i < 2; ++i) {                         \
      gll16(kw + hb + kgo[i] + (size_t)(T) * 64 * HD_, smem + (BASE) + klo_[i]); \
      gll16(vt + hb + vgo[i] + (T) * 64, smem + (BASE) + vlo_[i]);          \
    }                                                                       \
  }

  STAGE_KV(0, 0);
  __syncthreads();  // drains prologue staging + mask stores

  for (int t = 0; t < 32; ++t) {
    const int base = (t & 1) << 14;
    if (t < 31) {
      STAGE_KV(t + 1, ((t + 1) & 1) << 14);
      asm volatile("s_waitcnt vmcnt(4)" ::: "memory");
    } else {
      asm volatile("s_waitcnt vmcnt(0)" ::: "memory");
    }
    __builtin_amdgcn_s_barrier();
    __builtin_amdgcn_sched_barrier(0);

    // S^T = K Q^T : lane gets S[q=lr][kv = c*16 + lg*4 + r]
    f32x4 sc[2][4];
#pragma unroll
    for (int qb = 0; qb < 2; ++qb)
#pragma unroll
      for (int c = 0; c < 4; ++c) sc[qb][c] = (f32x4){0.f, 0.f, 0.f, 0.f};
    __builtin_amdgcn_s_setprio(1);
#pragma unroll
    for (int t2 = 0; t2 < 2; ++t2) {
#pragma unroll
      for (int c = 0; c < 4; ++c) {
        int off = base + ((c * 16 + lr) << 7) + ((t2 * 64 + lg * 16) ^ sw);
        bf16x8 kf = *(const bf16x8*)(smem + off);
        sc[0][c] = __builtin_amdgcn_mfma_f32_16x16x32_bf16(kf, aq[0][t2], sc[0][c], 0, 0, 0);
        sc[1][c] = __builtin_amdgcn_mfma_f32_16x16x32_bf16(kf, aq[1][t2], sc[1][c], 0, 0, 0);
      }
    }
    __builtin_amdgcn_s_setprio(0);

    f32x4 mk[4];
#pragma unroll
    for (int c = 0; c < 4; ++c)
      mk[c] = *(const f32x4*)(smem + MS + (t * 64 + c * 16 + lg * 4) * 4);

    // softmax (exp2 domain) + in-register P-fragment build
    bf16x8 pf[2][2];
#pragma unroll
    for (int qb = 0; qb < 2; ++qb) {
      float mx = -INFINITY;
#pragma unroll
      for (int c = 0; c < 4; ++c) {
        sc[qb][c] += mk[c];
#pragma unroll
        for (int r = 0; r < 4; ++r) mx = fmaxf(mx, sc[qb][c][r]);
      }
      mx = fmaxf(mx, __shfl_xor(mx, 16));
      mx = fmaxf(mx, __shfl_xor(mx, 32));
      if (mx > mrun[qb] + 8.f) {          // defer-max: tolerate p up to 2^8
        float corr = __builtin_amdgcn_exp2f(mrun[qb] - mx);
        mrun[qb] = mx;
        O4[qb] *= corr;
#pragma unroll
        for (int dt = 0; dt < 4; ++dt) O[qb][dt] *= corr;
      }
#pragma unroll
      for (int c = 0; c < 4; ++c)
#pragma unroll
        for (int r = 0; r < 4; ++r)
          sc[qb][c][r] = __builtin_amdgcn_exp2f(sc[qb][c][r] - mrun[qb]);

      // pack P (bf16 pairs) then redistribute: lane lg gets kv = kt*32 + lg*8 + j
#pragma unroll
      for (int kt = 0; kt < 2; ++kt) {
        unsigned int x0 = cvtpk(sc[qb][2 * kt][0], sc[qb][2 * kt][1]);
        unsigned int x1 = cvtpk(sc[qb][2 * kt + 1][0], sc[qb][2 * kt + 1][1]);
        unsigned int y0 = cvtpk(sc[qb][2 * kt][2], sc[qb][2 * kt][3]);
        unsigned int y1 = cvtpk(sc[qb][2 * kt + 1][2], sc[qb][2 * kt + 1][3]);
        swap32(x0, x1);
        swap16(x0, x1);
        swap32(y0, y1);
        swap16(y0, y1);
        u32x4 f = {x0, y0, x1, y1};
        pf[qb][kt] = *(bf16x8*)&f;
      }
    }

    // O^T += V^T P^T ; l accumulated as row 0 of the ones-MFMA
    __builtin_amdgcn_s_setprio(1);
#pragma unroll
    for (int kt = 0; kt < 2; ++kt) {
      O4[0] = __builtin_amdgcn_mfma_f32_16x16x32_bf16(ones_f, pf[0][kt], O4[0], 0, 0, 0);
      O4[1] = __builtin_amdgcn_mfma_f32_16x16x32_bf16(ones_f, pf[1][kt], O4[1], 0, 0, 0);
#pragma unroll
      for (int dt = 0; dt < 4; ++dt) {
        int off = base + 8192 + ((dt * 16 + lr) << 7) + ((kt * 64 + lg * 16) ^ sw);
        bf16x8 vf = *(const bf16x8*)(smem + off);
        O[0][dt] = __builtin_amdgcn_mfma_f32_16x16x32_bf16(vf, pf[0][kt], O[0][dt], 0, 0, 0);
        O[1][dt] = __builtin_amdgcn_mfma_f32_16x16x32_bf16(vf, pf[1][kt], O[1][dt], 0, 0, 0);
      }
    }
    __builtin_amdgcn_s_setprio(0);

    __builtin_amdgcn_sched_barrier(0);
    __builtin_amdgcn_s_barrier();
  }

  // epilogue: l = O4 row0 (lives at lg==0, reg 0, col=q) -> broadcast via shfl
#pragma unroll
  for (int qb = 0; qb < 2; ++qb) {
    float l = __shfl(O4[qb][0], lr, 64);
    float inv = 1.0f / l;
    int s = q0 + wave * 32 + qb * 16 + lr;
    size_t rowb = ((size_t)b * S_ + s) * HID_ + h * HD_;
#pragma unroll
    for (int dt = 0; dt < 4; ++dt) {
      float4 r;
      r.x = O[qb][dt][0] * inv;
      r.y = O[qb][dt][1] * inv;
      r.z = O[qb][dt][2] * inv;
      r.w = O[qb][dt][3] * inv;
      *(float4*)&outp[rowb + dt * 16 + lg * 4] = r;
    }
  }
#undef STAGE_KV
}

}  // namespace

extern "C" void kernel_launch(void* const* d_in, const int* in_sizes, int n_in,
                              void* d_out, int out_size, void* d_ws, size_t ws_size,
                              hipStream_t stream) {
  const float* hs   = (const float*)d_in[0];
  const float* mask = (const float*)d_in[1];
  const float* Wq   = (const float*)d_in[2];
  const float* bq   = (const float*)d_in[3];
  const float* Wk   = (const float*)d_in[4];
  const float* bk   = (const float*)d_in[5];
  const float* Wv   = (const float*)d_in[6];
  const float* bv   = (const float*)d_in[7];

  u16* qw = (u16*)d_ws;                  // [B,NH,S,HD] bf16 (rope + scale*log2e)
  u16* kw = qw + QSZ;                    // [B,NH,S,HD] bf16 (rope)
  u16* vt = kw + QSZ;                    // [B,NH,HD,S] bf16
  u16* hh = vt + QSZ;                    // [M, HID] bf16
  u16* wt = hh + (size_t)M_ * HID_;      // [3][1024][1024] transposed bf16
  float* ct = (float*)(wt + (size_t)3 * 1024 * 1024);
  float* st = ct + TBL;

  prep_kernel<<<5120, 256, 0, stream>>>(hs, hh, Wq, Wk, Wv, wt, ct, st);

  proj_gemm_kernel<<<768, 256, 0, stream>>>(hh, wt, bq, bk, bv, ct, st, qw, kw, vt);

  attn_mfma_kernel<<<512, 256, 0, stream>>>(qw, kw, vt, mask, (float*)d_out);
}